// Round 1
// baseline (1549.458 us; speedup 1.0000x reference)
//
#include <hip/hip_runtime.h>
#include <hip/hip_bf16.h>
#include <math.h>

#define N_NODES 100000
#define N_EDGES 1000000
#define IN_DIM 128
#define HID 64
#define NET 4
#define STEPS 5
#define G_GRAPHS 128
#define LBL 10

// ---------------- weight prep (once per call, tiny) ----------------
// Ws1[k][m] for m = t*64+o : trans[n][m] = sum_k h[n][k] * We[t][o][k]
__global__ void k_build_ws1(const float* __restrict__ We, const float* __restrict__ be,
                            float* __restrict__ Ws1, float* __restrict__ bs1) {
    int idx = blockIdx.x * blockDim.x + threadIdx.x; // 64*256
    if (idx >= 64 * 256) return;
    int k = idx >> 8, m = idx & 255;
    int t = m >> 6, o = m & 63;
    Ws1[k * 256 + m] = We[t * HID * HID + o * HID + k];
    if (k == 0) bs1[m] = be[t * HID + o];
}

// Fused GRU weight: A-row = [a(64) | h(64)], output cols m = q*64+c:
//  q=0: ir+hr, q=1: iz+hz, q=2: i_n (a only), q=3: h_n (h only)
__global__ void k_build_wg(const float* __restrict__ W_ih, const float* __restrict__ b_ih,
                           const float* __restrict__ W_hh, const float* __restrict__ b_hh,
                           float* __restrict__ Wg, float* __restrict__ bg) {
    int idx = blockIdx.x * blockDim.x + threadIdx.x; // 128*256
    if (idx >= 128 * 256) return;
    int k = idx >> 8, m = idx & 255;
    int q = m >> 6, c = m & 63;
    float v = 0.f;
    if (q == 0) { int j = c;       v = (k < 64) ? W_ih[j * 64 + k] : W_hh[j * 64 + (k - 64)]; }
    else if (q == 1) { int j = 64 + c;  v = (k < 64) ? W_ih[j * 64 + k] : W_hh[j * 64 + (k - 64)]; }
    else if (q == 2) { int j = 128 + c; v = (k < 64) ? W_ih[j * 64 + k] : 0.f; }
    else            { int j = 128 + c; v = (k < 64) ? 0.f : W_hh[j * 64 + (k - 64)]; }
    Wg[k * 256 + m] = v;
    if (k == 0) {
        float bv;
        if (q == 0) bv = b_ih[c] + b_hh[c];
        else if (q == 1) bv = b_ih[64 + c] + b_hh[64 + c];
        else if (q == 2) bv = b_ih[128 + c];
        else bv = b_hh[128 + c];
        bg[m] = bv;
    }
}

// ---------------- h0 = x @ W_in.T + b_in ----------------
__global__ __launch_bounds__(256) void k_linear_in(const float* __restrict__ x,
        const float* __restrict__ W_in, const float* __restrict__ b_in,
        float* __restrict__ ah) {
    __shared__ float wl[64 * 129];  // padded: bank = (o+k)%32, 2-way (free)
    __shared__ float xl[4 * 128];
    for (int i = threadIdx.x; i < 64 * 128; i += 256) {
        int o = i >> 7, k = i & 127;
        wl[o * 129 + k] = W_in[i];
    }
    __syncthreads();
    int nl = threadIdx.x >> 6, o = threadIdx.x & 63;
    float bo = b_in[o];
    for (int base = blockIdx.x * 4; base < N_NODES; base += gridDim.x * 4) {
        int n = base + nl;
        if (n < N_NODES) {
            xl[nl * 128 + o] = x[n * 128 + o];
            xl[nl * 128 + 64 + o] = x[n * 128 + 64 + o];
        }
        __syncthreads();
        if (n < N_NODES) {
            float acc = 0.f;
            #pragma unroll 8
            for (int k = 0; k < 128; ++k)
                acc = fmaf(xl[nl * 128 + k], wl[o * 129 + k], acc);
            ah[n * 128 + 64 + o] = acc + bo;  // h region = cols 64..127
        }
        __syncthreads();
    }
}

// ---------------- CSR build (once per call) ----------------
__global__ void k_hist(const int* __restrict__ dst, int* __restrict__ deg) {
    int e = blockIdx.x * blockDim.x + threadIdx.x;
    if (e < N_EDGES) atomicAdd(&deg[dst[e]], 1);
}

__global__ __launch_bounds__(256) void k_scan1(const int* __restrict__ deg,
        int* __restrict__ ex, int* __restrict__ bsum, int n) {
    __shared__ int ts[256];
    int base = blockIdx.x * 1024;
    int vals[4]; int s = 0;
    #pragma unroll
    for (int i = 0; i < 4; ++i) {
        int idx = base + threadIdx.x * 4 + i;
        vals[i] = (idx < n) ? deg[idx] : 0;
        s += vals[i];
    }
    ts[threadIdx.x] = s;
    __syncthreads();
    for (int off = 1; off < 256; off <<= 1) {
        int v = (threadIdx.x >= off) ? ts[threadIdx.x - off] : 0;
        __syncthreads();
        ts[threadIdx.x] += v;
        __syncthreads();
    }
    int run = (threadIdx.x == 0) ? 0 : ts[threadIdx.x - 1];
    #pragma unroll
    for (int i = 0; i < 4; ++i) {
        int idx = base + threadIdx.x * 4 + i;
        if (idx < n) ex[idx] = run;
        run += vals[i];
    }
    if (threadIdx.x == 255) bsum[blockIdx.x] = ts[255];
}

__global__ void k_scan2(int* bsum, int nb, int* row_ptr_end) {
    if (threadIdx.x == 0 && blockIdx.x == 0) {
        int run = 0;
        for (int i = 0; i < nb; ++i) { int t = bsum[i]; bsum[i] = run; run += t; }
        *row_ptr_end = run;  // row_ptr[N] = E
    }
}

__global__ void k_scan3(int* __restrict__ row_ptr, int* __restrict__ cursor,
                        const int* __restrict__ bsum, int n) {
    int i = blockIdx.x * blockDim.x + threadIdx.x;
    if (i < n) {
        int v = row_ptr[i] + bsum[i >> 10];
        row_ptr[i] = v;
        cursor[i] = v;
    }
}

__global__ void k_fill(const int* __restrict__ src, const int* __restrict__ dst,
                       const int* __restrict__ et, int* __restrict__ cursor,
                       int* __restrict__ adj) {
    int e = blockIdx.x * blockDim.x + threadIdx.x;
    if (e < N_EDGES) {
        int d = dst[e];
        int p = atomicAdd(&cursor[d], 1);
        adj[p] = src[e] | (et[e] << 20);  // src < 2^17, et < 4
    }
}

// ---------------- tiled fp32 GEMM [nrows,K] x [K,256], BM=64, BK=16 ----------------
// EPI 0: C[n*256+m] = acc + bias[m]      (trans)
// EPI 1: GRU epilogue, writes h_new into ah[n*128+64+m], m in [0,64)
template<int K, int EPI>
__global__ __launch_bounds__(256) void k_gemm(const float* __restrict__ A, int lda,
        const float* __restrict__ B, const float* __restrict__ bias,
        float* __restrict__ C, float* __restrict__ ah, int nrows) {
    __shared__ float As[16 * 68];    // As[k][r], padded
    __shared__ float Bs[16 * 260];   // Bs[k][m], padded
    int tid = threadIdx.x;
    int tr = tid >> 4, tc = tid & 15;
    int n0 = blockIdx.x * 64;
    float acc[4][16];
    #pragma unroll
    for (int i = 0; i < 4; ++i)
        #pragma unroll
        for (int j = 0; j < 16; ++j) acc[i][j] = 0.f;

    for (int k0 = 0; k0 < K; k0 += 16) {
        {   // stage A (transposed into LDS)
            int r = tid >> 2, kk = (tid & 3) << 2;
            float4 av = make_float4(0.f, 0.f, 0.f, 0.f);
            if (n0 + r < nrows)
                av = *(const float4*)&A[(size_t)(n0 + r) * lda + k0 + kk];
            As[(kk + 0) * 68 + r] = av.x;
            As[(kk + 1) * 68 + r] = av.y;
            As[(kk + 2) * 68 + r] = av.z;
            As[(kk + 3) * 68 + r] = av.w;
            // stage B
            int bk = tid >> 4, bc = (tid & 15) << 4;
            const float4* bp = (const float4*)&B[(k0 + bk) * 256 + bc];
            float4 b0 = bp[0], b1 = bp[1], b2 = bp[2], b3 = bp[3];
            *(float4*)&Bs[bk * 260 + bc + 0] = b0;
            *(float4*)&Bs[bk * 260 + bc + 4] = b1;
            *(float4*)&Bs[bk * 260 + bc + 8] = b2;
            *(float4*)&Bs[bk * 260 + bc + 12] = b3;
        }
        __syncthreads();
        #pragma unroll
        for (int k = 0; k < 16; ++k) {
            float4 a4 = *(const float4*)&As[k * 68 + tr * 4];
            float av[4] = {a4.x, a4.y, a4.z, a4.w};
            #pragma unroll
            for (int q = 0; q < 4; ++q) {
                float4 b4 = *(const float4*)&Bs[k * 260 + q * 64 + tc * 4];
                float bv[4] = {b4.x, b4.y, b4.z, b4.w};
                #pragma unroll
                for (int i = 0; i < 4; ++i)
                    #pragma unroll
                    for (int c = 0; c < 4; ++c)
                        acc[i][q * 4 + c] = fmaf(av[i], bv[c], acc[i][q * 4 + c]);
            }
        }
        __syncthreads();
    }

    if (EPI == 0) {
        #pragma unroll
        for (int i = 0; i < 4; ++i) {
            int n = n0 + tr * 4 + i;
            if (n >= nrows) continue;
            #pragma unroll
            for (int q = 0; q < 4; ++q) {
                int m = q * 64 + tc * 4;
                float4 o;
                o.x = acc[i][q * 4 + 0] + bias[m + 0];
                o.y = acc[i][q * 4 + 1] + bias[m + 1];
                o.z = acc[i][q * 4 + 2] + bias[m + 2];
                o.w = acc[i][q * 4 + 3] + bias[m + 3];
                *(float4*)&C[(size_t)n * 256 + m] = o;
            }
        }
    } else {
        #pragma unroll
        for (int i = 0; i < 4; ++i) {
            int n = n0 + tr * 4 + i;
            if (n >= nrows) continue;
            float4 hold = *(const float4*)&ah[(size_t)n * 128 + 64 + tc * 4];
            float ho[4] = {hold.x, hold.y, hold.z, hold.w};
            float4 o;
            float* op = &o.x;
            #pragma unroll
            for (int c = 0; c < 4; ++c) {
                int m = tc * 4 + c;
                float rs  = acc[i][0 * 4 + c] + bias[m];
                float zs  = acc[i][1 * 4 + c] + bias[64 + m];
                float inn = acc[i][2 * 4 + c] + bias[128 + m];
                float hn  = acc[i][3 * 4 + c] + bias[192 + m];
                float r = 1.f / (1.f + __expf(-rs));
                float z = 1.f / (1.f + __expf(-zs));
                float nn = tanhf(inn + r * hn);
                op[c] = (1.f - z) * nn + z * ho[c];
            }
            *(float4*)&ah[(size_t)n * 128 + 64 + tc * 4] = o;
        }
    }
}

// ---------------- per-node aggregation via CSR (one wave per node) ----------------
__global__ __launch_bounds__(256) void k_aggregate(const int* __restrict__ row_ptr,
        const int* __restrict__ adj, const float* __restrict__ trans,
        float* __restrict__ ah) {
    int w = threadIdx.x >> 6, lane = threadIdx.x & 63;
    int n = blockIdx.x * 4 + w;
    if (n >= N_NODES) return;
    int beg = row_ptr[n], end = row_ptr[n + 1];
    float acc = 0.f;
    for (int i = beg; i < end; ++i) {
        int pk = adj[i];                 // same addr across wave -> broadcast
        int s = pk & 0xFFFFF;
        int et = pk >> 20;
        acc += trans[(size_t)s * 256 + et * 64 + lane];  // 256B coalesced
    }
    ah[(size_t)n * 128 + lane] = acc;    // a region = cols 0..63
}

// ---------------- per-graph mean pooling (node2graph sorted) ----------------
__global__ __launch_bounds__(256) void k_pool(const int* __restrict__ n2g,
        const float* __restrict__ ah, float* __restrict__ hg) {
    int g = blockIdx.x;
    int lo = 0, hi = N_NODES;
    while (lo < hi) { int mid = (lo + hi) >> 1; if (n2g[mid] < g) lo = mid + 1; else hi = mid; }
    int s = lo;
    hi = N_NODES;
    while (lo < hi) { int mid = (lo + hi) >> 1; if (n2g[mid] < g + 1) lo = mid + 1; else hi = mid; }
    int e = lo;
    int w = threadIdx.x >> 6, lane = threadIdx.x & 63;
    float sum = 0.f;
    for (int n = s + w; n < e; n += 4) sum += ah[(size_t)n * 128 + 64 + lane];
    __shared__ float red[4][64];
    red[w][lane] = sum;
    __syncthreads();
    if (threadIdx.x < 64) {
        float tot = red[0][lane] + red[1][lane] + red[2][lane] + red[3][lane];
        float cnt = (float)(e - s);
        hg[g * 64 + lane] = tot / fmaxf(cnt, 1.f);
    }
}

// ---------------- classifier ----------------
__global__ __launch_bounds__(64) void k_cls(const float* __restrict__ hg,
        const float* __restrict__ W1, const float* __restrict__ b1,
        const float* __restrict__ W2, const float* __restrict__ b2,
        float* __restrict__ out) {
    int g = blockIdx.x;
    __shared__ float v[64];
    __shared__ float m[32];
    v[threadIdx.x] = hg[g * 64 + threadIdx.x];
    __syncthreads();
    if (threadIdx.x < 32) {
        float a = b1[threadIdx.x];
        #pragma unroll 8
        for (int k = 0; k < 64; ++k) a = fmaf(v[k], W1[threadIdx.x * 64 + k], a);
        m[threadIdx.x] = fmaxf(a, 0.f);
    }
    __syncthreads();
    if (threadIdx.x < 10) {
        float a = b2[threadIdx.x];
        #pragma unroll
        for (int j = 0; j < 32; ++j) a = fmaf(m[j], W2[threadIdx.x * 32 + j], a);
        out[g * 10 + threadIdx.x] = a;
    }
}

extern "C" void kernel_launch(void* const* d_in, const int* in_sizes, int n_in,
                              void* d_out, int out_size, void* d_ws, size_t ws_size,
                              hipStream_t stream) {
    const float* x    = (const float*)d_in[0];
    const int* src    = (const int*)d_in[1];
    const int* dst    = (const int*)d_in[2];
    const int* etype  = (const int*)d_in[3];
    const int* n2g    = (const int*)d_in[4];
    const float* W_in = (const float*)d_in[5];
    const float* b_in = (const float*)d_in[6];
    const float* We   = (const float*)d_in[7];
    const float* be   = (const float*)d_in[8];
    const float* W_ih = (const float*)d_in[9];
    const float* b_ih = (const float*)d_in[10];
    const float* W_hh = (const float*)d_in[11];
    const float* b_hh = (const float*)d_in[12];
    const float* W1   = (const float*)d_in[13];
    const float* b1   = (const float*)d_in[14];
    const float* W2   = (const float*)d_in[15];
    const float* b2   = (const float*)d_in[16];
    float* out = (float*)d_out;

    char* wsb = (char*)d_ws;
    size_t off = 0;
    auto alloc = [&](size_t bytes) -> void* {
        void* p = wsb + off;
        off += (bytes + 255) & ~(size_t)255;
        return p;
    };
    float* trans   = (float*)alloc((size_t)N_NODES * 256 * 4);   // 102.4 MB
    float* ah      = (float*)alloc((size_t)N_NODES * 128 * 4);   // 51.2 MB: [a(64)|h(64)] per node
    int*   adj     = (int*)  alloc((size_t)N_EDGES * 4);
    int*   row_ptr = (int*)  alloc((size_t)(N_NODES + 1) * 4);
    int*   cursor  = (int*)  alloc((size_t)N_NODES * 4);
    int*   deg     = (int*)  alloc((size_t)N_NODES * 4);
    int*   bsum    = (int*)  alloc(1024);
    float* Ws1     = (float*)alloc(64 * 256 * 4);
    float* bs1     = (float*)alloc(256 * 4);
    float* Wg      = (float*)alloc(128 * 256 * 4);
    float* bg      = (float*)alloc(256 * 4);
    float* hg      = (float*)alloc(128 * 64 * 4);

    // weight prep
    hipLaunchKernelGGL(k_build_ws1, dim3(64), dim3(256), 0, stream, We, be, Ws1, bs1);
    hipLaunchKernelGGL(k_build_wg, dim3(128), dim3(256), 0, stream, W_ih, b_ih, W_hh, b_hh, Wg, bg);
    // h0
    hipLaunchKernelGGL(k_linear_in, dim3(1024), dim3(256), 0, stream, x, W_in, b_in, ah);
    // CSR build
    hipMemsetAsync(deg, 0, (size_t)N_NODES * 4, stream);
    hipLaunchKernelGGL(k_hist, dim3((N_EDGES + 255) / 256), dim3(256), 0, stream, dst, deg);
    int nblk = (N_NODES + 1023) / 1024;
    hipLaunchKernelGGL(k_scan1, dim3(nblk), dim3(256), 0, stream, deg, row_ptr, bsum, N_NODES);
    hipLaunchKernelGGL(k_scan2, dim3(1), dim3(64), 0, stream, bsum, nblk, row_ptr + N_NODES);
    hipLaunchKernelGGL(k_scan3, dim3((N_NODES + 255) / 256), dim3(256), 0, stream, row_ptr, cursor, bsum, N_NODES);
    hipLaunchKernelGGL(k_fill, dim3((N_EDGES + 255) / 256), dim3(256), 0, stream, src, dst, etype, cursor, adj);

    int gblk = (N_NODES + 63) / 64;
    for (int step = 0; step < STEPS; ++step) {
        hipLaunchKernelGGL((k_gemm<64, 0>), dim3(gblk), dim3(256), 0, stream,
                           ah + 64, 128, Ws1, bs1, trans, ah, N_NODES);
        hipLaunchKernelGGL(k_aggregate, dim3((N_NODES + 3) / 4), dim3(256), 0, stream,
                           row_ptr, adj, trans, ah);
        hipLaunchKernelGGL((k_gemm<128, 1>), dim3(gblk), dim3(256), 0, stream,
                           ah, 128, Wg, bg, trans, ah, N_NODES);
    }
    hipLaunchKernelGGL(k_pool, dim3(G_GRAPHS), dim3(256), 0, stream, n2g, ah, hg);
    hipLaunchKernelGGL(k_cls, dim3(G_GRAPHS), dim3(64), 0, stream, hg, W1, b1, W2, b2, out);
}

// Round 2
// 1367.045 us; speedup vs baseline: 1.1334x; 1.1334x over previous
//
#include <hip/hip_runtime.h>
#include <hip/hip_bf16.h>
#include <math.h>

#define N_NODES 100000
#define N_EDGES 1000000
#define IN_DIM 128
#define HID 64
#define NET 4
#define STEPS 5
#define G_GRAPHS 128
#define LBL 10

typedef __attribute__((ext_vector_type(8))) short short8;
typedef __attribute__((ext_vector_type(4))) float f32x4;
typedef unsigned short ushort_t;

__device__ inline ushort_t f2bf(float v) {
    __hip_bfloat16 b = __float2bfloat16(v);
    return __builtin_bit_cast(ushort_t, b);
}
__device__ inline float bf2f(ushort_t u) {
    __hip_bfloat16 b = __builtin_bit_cast(__hip_bfloat16, u);
    return __bfloat162float(b);
}

// ---------------- pack B1: We -> [6 slices][16 ct][4 g][16 u][8 j] bf16 ----------------
// GEMM1: C = Hhi*Whi + Hlo*Whi + Hhi*Wlo ; slices 0,1: Whi k 0..63 ; 2,3: Whi again ; 4,5: Wlo
// col m = t*64 + o (identity layout). Also builds bs1.
__global__ void k_pack_b1(const float* __restrict__ We, const float* __restrict__ be,
                          ushort_t* __restrict__ B1, float* __restrict__ bs1) {
    int idx = blockIdx.x * blockDim.x + threadIdx.x;
    if (idx >= 6 * 16 * 4 * 16 * 8) return;
    int j = idx & 7, u = (idx >> 3) & 15, g = (idx >> 7) & 3, ct = (idx >> 9) & 15, s = idx >> 13;
    int m = ct * 16 + u;
    int t = m >> 6, o = m & 63;
    int sk = (s < 2) ? s : (s < 4) ? (s - 2) : (s - 4);
    int k = sk * 32 + g * 8 + j;
    float val = We[t * 4096 + o * 64 + k];
    ushort_t hi = f2bf(val);
    B1[idx] = (s < 4) ? hi : f2bf(val - bf2f(hi));
    if (s == 0 && g == 0 && j == 0) bs1[m] = be[t * 64 + o];
}

// ---------------- pack B2: GRU fused weight -> [12][16][4][16][8] bf16 ----------------
// A-row = [a(64)|h(64)]; new col layout m = q*64 + gate*16 + u  -> gate of hidden unit q*16+u
// slices 0..3: Whi ; 4..7: Whi ; 8..11: Wlo   (k = (s&3)*32 + g*8 + j)
__global__ void k_pack_b2(const float* __restrict__ W_ih, const float* __restrict__ b_ih,
                          const float* __restrict__ W_hh, const float* __restrict__ b_hh,
                          ushort_t* __restrict__ B2, float* __restrict__ bg2) {
    int idx = blockIdx.x * blockDim.x + threadIdx.x;
    if (idx >= 12 * 16 * 4 * 16 * 8) return;
    int j = idx & 7, u = (idx >> 3) & 15, g = (idx >> 7) & 3, ct = (idx >> 9) & 15, s = idx >> 13;
    int m = ct * 16 + u;
    int q = m >> 6, gate = (m >> 4) & 3, c = q * 16 + (m & 15);
    int k = (s & 3) * 32 + g * 8 + j;
    float val;
    if (gate == 0)      { int jr = c;        val = (k < 64) ? W_ih[jr * 64 + k] : W_hh[jr * 64 + k - 64]; }
    else if (gate == 1) { int jr = 64 + c;   val = (k < 64) ? W_ih[jr * 64 + k] : W_hh[jr * 64 + k - 64]; }
    else if (gate == 2) { int jr = 128 + c;  val = (k < 64) ? W_ih[jr * 64 + k] : 0.f; }
    else                { int jr = 128 + c;  val = (k < 64) ? 0.f : W_hh[jr * 64 + k - 64]; }
    ushort_t hi = f2bf(val);
    B2[idx] = (s < 8) ? hi : f2bf(val - bf2f(hi));
    if (s == 0 && g == 0 && j == 0) {
        float bv;
        if (gate == 0)      bv = b_ih[c] + b_hh[c];
        else if (gate == 1) bv = b_ih[64 + c] + b_hh[64 + c];
        else if (gate == 2) bv = b_ih[128 + c];
        else                bv = b_hh[128 + c];
        bg2[m] = bv;
    }
}

// ---------------- h0 = x @ W_in.T + b_in (fp32, runs once) ----------------
__global__ __launch_bounds__(256) void k_linear_in(const float* __restrict__ x,
        const float* __restrict__ W_in, const float* __restrict__ b_in,
        float* __restrict__ ah) {
    __shared__ float wl[64 * 129];
    __shared__ float xl[4 * 128];
    for (int i = threadIdx.x; i < 64 * 128; i += 256) {
        int o = i >> 7, k = i & 127;
        wl[o * 129 + k] = W_in[i];
    }
    __syncthreads();
    int nl = threadIdx.x >> 6, o = threadIdx.x & 63;
    float bo = b_in[o];
    for (int base = blockIdx.x * 4; base < N_NODES; base += gridDim.x * 4) {
        int n = base + nl;
        if (n < N_NODES) {
            xl[nl * 128 + o] = x[n * 128 + o];
            xl[nl * 128 + 64 + o] = x[n * 128 + 64 + o];
        }
        __syncthreads();
        if (n < N_NODES) {
            float acc = 0.f;
            #pragma unroll 8
            for (int k = 0; k < 128; ++k)
                acc = fmaf(xl[nl * 128 + k], wl[o * 129 + k], acc);
            ah[(size_t)n * 128 + 64 + o] = acc + bo;
        }
        __syncthreads();
    }
}

// ---------------- CSR build (once per call) ----------------
__global__ void k_hist(const int* __restrict__ dst, int* __restrict__ deg) {
    int e = blockIdx.x * blockDim.x + threadIdx.x;
    if (e < N_EDGES) atomicAdd(&deg[dst[e]], 1);
}

__global__ __launch_bounds__(256) void k_scan1(const int* __restrict__ deg,
        int* __restrict__ ex, int* __restrict__ bsum, int n) {
    __shared__ int ts[256];
    int base = blockIdx.x * 1024;
    int vals[4]; int s = 0;
    #pragma unroll
    for (int i = 0; i < 4; ++i) {
        int idx = base + threadIdx.x * 4 + i;
        vals[i] = (idx < n) ? deg[idx] : 0;
        s += vals[i];
    }
    ts[threadIdx.x] = s;
    __syncthreads();
    for (int off = 1; off < 256; off <<= 1) {
        int v = (threadIdx.x >= off) ? ts[threadIdx.x - off] : 0;
        __syncthreads();
        ts[threadIdx.x] += v;
        __syncthreads();
    }
    int run = (threadIdx.x == 0) ? 0 : ts[threadIdx.x - 1];
    #pragma unroll
    for (int i = 0; i < 4; ++i) {
        int idx = base + threadIdx.x * 4 + i;
        if (idx < n) ex[idx] = run;
        run += vals[i];
    }
    if (threadIdx.x == 255) bsum[blockIdx.x] = ts[255];
}

__global__ void k_scan2(int* bsum, int nb, int* row_ptr_end) {
    if (threadIdx.x == 0 && blockIdx.x == 0) {
        int run = 0;
        for (int i = 0; i < nb; ++i) { int t = bsum[i]; bsum[i] = run; run += t; }
        *row_ptr_end = run;
    }
}

__global__ void k_scan3(int* __restrict__ row_ptr, int* __restrict__ cursor,
                        const int* __restrict__ bsum, int n) {
    int i = blockIdx.x * blockDim.x + threadIdx.x;
    if (i < n) {
        int v = row_ptr[i] + bsum[i >> 10];
        row_ptr[i] = v;
        cursor[i] = v;
    }
}

__global__ void k_fill(const int* __restrict__ src, const int* __restrict__ dst,
                       const int* __restrict__ et, int* __restrict__ cursor,
                       int* __restrict__ adj) {
    int e = blockIdx.x * blockDim.x + threadIdx.x;
    if (e < N_EDGES) {
        int d = dst[e];
        int p = atomicAdd(&cursor[d], 1);
        adj[p] = src[e] | (et[e] << 20);
    }
}

// ---------------- GEMM1: trans[N,256](bf16) = split3(h[N,64]) x B1 ----------------
// 128 rows/block, 512 threads = 8 waves: wave = (rp row-panel 0..1, q col-quadrant 0..3)
__global__ __launch_bounds__(512) void k_mm1(const float* __restrict__ ah,
        const ushort_t* __restrict__ B1, const float* __restrict__ bs1,
        ushort_t* __restrict__ trans) {
    __shared__ ushort_t lds[16896];   // max(128*128 A, 64*264 epi)
    int tid = threadIdx.x;
    int n0 = blockIdx.x * 128;
    {   // stage A: hi|lo split of h, XOR-swizzled 16B blocks
        int rl = tid >> 2, c0 = (tid & 3) * 16;
        const float* srcp = &ah[(size_t)(n0 + rl) * 128 + 64 + c0];
        bool ok = (n0 + rl) < N_NODES;
        #pragma unroll
        for (int i = 0; i < 2; ++i) {
            short8 bh, bl;
            #pragma unroll
            for (int j = 0; j < 8; ++j) {
                float v = ok ? srcp[i * 8 + j] : 0.f;
                ushort_t hh = f2bf(v);
                bh[j] = (short)hh;
                bl[j] = (short)f2bf(v - bf2f(hh));
            }
            int b = (c0 >> 3) + i;                    // hi block 0..7
            *(short8*)&lds[rl * 128 + ((b      ) ^ (rl & 15)) * 8] = bh;
            *(short8*)&lds[rl * 128 + ((b + 8  ) ^ (rl & 15)) * 8] = bl;
        }
    }
    __syncthreads();
    int lane = tid & 63, wp = tid >> 6;
    int q = wp & 3, rp = wp >> 2;
    int g = lane >> 4, u = lane & 15;
    f32x4 zero = {0.f, 0.f, 0.f, 0.f};
    f32x4 acc[4][4];
    #pragma unroll
    for (int i = 0; i < 4; ++i)
        #pragma unroll
        for (int j = 0; j < 4; ++j) acc[i][j] = zero;
    const int bb[6] = {0, 4, 8, 12, 0, 4};            // A block base per slice
    #pragma unroll
    for (int s = 0; s < 6; ++s) {
        short8 bfr[4], afr[4];
        #pragma unroll
        for (int ct = 0; ct < 4; ++ct)
            bfr[ct] = *(const short8*)&B1[((size_t)(s * 16 + q * 4 + ct) * 64 + g * 16 + u) * 8];
        int b0 = bb[s] + g;
        #pragma unroll
        for (int rt = 0; rt < 4; ++rt) {
            int rl = rp * 64 + rt * 16 + u;
            afr[rt] = *(const short8*)&lds[rl * 128 + (b0 ^ u) * 8];
        }
        #pragma unroll
        for (int rt = 0; rt < 4; ++rt)
            #pragma unroll
            for (int ct = 0; ct < 4; ++ct)
                acc[rt][ct] = __builtin_amdgcn_mfma_f32_16x16x32_bf16(afr[rt], bfr[ct], acc[rt][ct], 0, 0, 0);
    }
    float bsv[4];
    #pragma unroll
    for (int ct = 0; ct < 4; ++ct) bsv[ct] = bs1[q * 64 + ct * 16 + u];
    // epilogue: assemble bf16 rows in LDS (two 64-row halves), coalesced copy out
    #pragma unroll
    for (int h = 0; h < 2; ++h) {
        __syncthreads();
        if (rp == h) {
            #pragma unroll
            for (int rt = 0; rt < 4; ++rt)
                #pragma unroll
                for (int ct = 0; ct < 4; ++ct)
                    #pragma unroll
                    for (int j = 0; j < 4; ++j) {
                        int rl = rt * 16 + g * 4 + j;
                        lds[rl * 264 + q * 64 + ct * 16 + u] = f2bf(acc[rt][ct][j] + bsv[ct]);
                    }
        }
        __syncthreads();
        int rl = tid >> 3, seg = tid & 7;
        int n = n0 + h * 64 + rl;
        if (n < N_NODES) {
            #pragma unroll
            for (int i = 0; i < 4; ++i) {
                short8 v = *(const short8*)&lds[rl * 264 + seg * 32 + i * 8];
                *(short8*)&trans[(size_t)n * 256 + seg * 32 + i * 8] = v;
            }
        }
    }
}

// ---------------- GEMM2 + GRU: h = GRU(a,h), A=[a|h] split3 x B2, in-place ----------------
__global__ __launch_bounds__(512) void k_mm2(float* __restrict__ ah,
        const ushort_t* __restrict__ B2, const float* __restrict__ bg2) {
    __shared__ ushort_t lds[128 * 256];   // 64KB
    int tid = threadIdx.x;
    int n0 = blockIdx.x * 128;
    {
        int rl = tid >> 2, c0 = (tid & 3) * 32;
        const float* srcp = &ah[(size_t)(n0 + rl) * 128 + c0];
        bool ok = (n0 + rl) < N_NODES;
        #pragma unroll
        for (int i = 0; i < 4; ++i) {
            short8 bh, bl;
            #pragma unroll
            for (int j = 0; j < 8; ++j) {
                float v = ok ? srcp[i * 8 + j] : 0.f;
                ushort_t hh = f2bf(v);
                bh[j] = (short)hh;
                bl[j] = (short)f2bf(v - bf2f(hh));
            }
            int b = (c0 >> 3) + i;                    // hi block 0..15
            *(short8*)&lds[rl * 256 + ((b       ) ^ (rl & 15)) * 8] = bh;
            *(short8*)&lds[rl * 256 + ((b + 16  ) ^ (rl & 15)) * 8] = bl;
        }
    }
    __syncthreads();
    int lane = tid & 63, wp = tid >> 6;
    int q = wp & 3, rp = wp >> 2;
    int g = lane >> 4, u = lane & 15;
    f32x4 zero = {0.f, 0.f, 0.f, 0.f};
    f32x4 acc[4][4];
    #pragma unroll
    for (int i = 0; i < 4; ++i)
        #pragma unroll
        for (int j = 0; j < 4; ++j) acc[i][j] = zero;
    const int bb[12] = {0, 4, 8, 12, 16, 20, 24, 28, 0, 4, 8, 12};
    #pragma unroll
    for (int s = 0; s < 12; ++s) {
        short8 bfr[4], afr[4];
        #pragma unroll
        for (int ct = 0; ct < 4; ++ct)
            bfr[ct] = *(const short8*)&B2[((size_t)(s * 16 + q * 4 + ct) * 64 + g * 16 + u) * 8];
        int b0 = bb[s] + g;
        #pragma unroll
        for (int rt = 0; rt < 4; ++rt) {
            int rl = rp * 64 + rt * 16 + u;
            afr[rt] = *(const short8*)&lds[rl * 256 + (b0 ^ u) * 8];
        }
        #pragma unroll
        for (int rt = 0; rt < 4; ++rt)
            #pragma unroll
            for (int ct = 0; ct < 4; ++ct)
                acc[rt][ct] = __builtin_amdgcn_mfma_f32_16x16x32_bf16(afr[rt], bfr[ct], acc[rt][ct], 0, 0, 0);
    }
    // GRU epilogue: ct = gate (0:r 1:z 2:in 3:hn), hidden unit = q*16+u
    float bgv[4];
    #pragma unroll
    for (int ct = 0; ct < 4; ++ct) bgv[ct] = bg2[q * 64 + ct * 16 + u];
    int hid = q * 16 + u;
    int bhi = 8 + (hid >> 3);          // hi block of A col 64+hid
    int blo = bhi + 16;
    int elem = hid & 7;
    #pragma unroll
    for (int rt = 0; rt < 4; ++rt) {
        #pragma unroll
        for (int j = 0; j < 4; ++j) {
            int rl = rp * 64 + rt * 16 + g * 4 + j;
            int n = n0 + rl;
            float rs  = acc[rt][0][j] + bgv[0];
            float zs  = acc[rt][1][j] + bgv[1];
            float inn = acc[rt][2][j] + bgv[2];
            float hnn = acc[rt][3][j] + bgv[3];
            ushort_t hh = lds[rl * 256 + (bhi ^ (rl & 15)) * 8 + elem];
            ushort_t hl = lds[rl * 256 + (blo ^ (rl & 15)) * 8 + elem];
            float ho = bf2f(hh) + bf2f(hl);
            float r = 1.f / (1.f + __expf(-rs));
            float z = 1.f / (1.f + __expf(-zs));
            float nn = tanhf(inn + r * hnn);
            if (n < N_NODES) ah[(size_t)n * 128 + 64 + hid] = (1.f - z) * nn + z * ho;
        }
    }
}

// ---------------- per-node aggregation via CSR (one wave per node) ----------------
__global__ __launch_bounds__(256) void k_aggregate(const int* __restrict__ row_ptr,
        const int* __restrict__ adj, const ushort_t* __restrict__ trans,
        float* __restrict__ ah) {
    int w = threadIdx.x >> 6, lane = threadIdx.x & 63;
    int n = blockIdx.x * 4 + w;
    if (n >= N_NODES) return;
    int beg = row_ptr[n], end = row_ptr[n + 1];
    float acc = 0.f;
    for (int i = beg; i < end; ++i) {
        int pk = adj[i];
        int s = pk & 0xFFFFF;
        int et = pk >> 20;
        acc += bf2f(trans[(size_t)s * 256 + et * 64 + lane]);
    }
    ah[(size_t)n * 128 + lane] = acc;
}

// ---------------- per-graph mean pooling (node2graph sorted) ----------------
__global__ __launch_bounds__(256) void k_pool(const int* __restrict__ n2g,
        const float* __restrict__ ah, float* __restrict__ hg) {
    int gidx = blockIdx.x;
    int lo = 0, hi = N_NODES;
    while (lo < hi) { int mid = (lo + hi) >> 1; if (n2g[mid] < gidx) lo = mid + 1; else hi = mid; }
    int s = lo;
    hi = N_NODES;
    while (lo < hi) { int mid = (lo + hi) >> 1; if (n2g[mid] < gidx + 1) lo = mid + 1; else hi = mid; }
    int e = lo;
    int w = threadIdx.x >> 6, lane = threadIdx.x & 63;
    float sum = 0.f;
    for (int n = s + w; n < e; n += 4) sum += ah[(size_t)n * 128 + 64 + lane];
    __shared__ float red[4][64];
    red[w][lane] = sum;
    __syncthreads();
    if (threadIdx.x < 64) {
        float tot = red[0][lane] + red[1][lane] + red[2][lane] + red[3][lane];
        float cnt = (float)(e - s);
        hg[gidx * 64 + lane] = tot / fmaxf(cnt, 1.f);
    }
}

// ---------------- classifier ----------------
__global__ __launch_bounds__(64) void k_cls(const float* __restrict__ hg,
        const float* __restrict__ W1, const float* __restrict__ b1,
        const float* __restrict__ W2, const float* __restrict__ b2,
        float* __restrict__ out) {
    int gidx = blockIdx.x;
    __shared__ float v[64];
    __shared__ float m[32];
    v[threadIdx.x] = hg[gidx * 64 + threadIdx.x];
    __syncthreads();
    if (threadIdx.x < 32) {
        float a = b1[threadIdx.x];
        #pragma unroll 8
        for (int k = 0; k < 64; ++k) a = fmaf(v[k], W1[threadIdx.x * 64 + k], a);
        m[threadIdx.x] = fmaxf(a, 0.f);
    }
    __syncthreads();
    if (threadIdx.x < 10) {
        float a = b2[threadIdx.x];
        #pragma unroll
        for (int j = 0; j < 32; ++j) a = fmaf(m[j], W2[threadIdx.x * 32 + j], a);
        out[gidx * 10 + threadIdx.x] = a;
    }
}

extern "C" void kernel_launch(void* const* d_in, const int* in_sizes, int n_in,
                              void* d_out, int out_size, void* d_ws, size_t ws_size,
                              hipStream_t stream) {
    const float* x    = (const float*)d_in[0];
    const int* src    = (const int*)d_in[1];
    const int* dst    = (const int*)d_in[2];
    const int* etype  = (const int*)d_in[3];
    const int* n2g    = (const int*)d_in[4];
    const float* W_in = (const float*)d_in[5];
    const float* b_in = (const float*)d_in[6];
    const float* We   = (const float*)d_in[7];
    const float* be   = (const float*)d_in[8];
    const float* W_ih = (const float*)d_in[9];
    const float* b_ih = (const float*)d_in[10];
    const float* W_hh = (const float*)d_in[11];
    const float* b_hh = (const float*)d_in[12];
    const float* W1   = (const float*)d_in[13];
    const float* b1   = (const float*)d_in[14];
    const float* W2   = (const float*)d_in[15];
    const float* b2   = (const float*)d_in[16];
    float* out = (float*)d_out;

    char* wsb = (char*)d_ws;
    size_t off = 0;
    auto alloc = [&](size_t bytes) -> void* {
        void* p = wsb + off;
        off += (bytes + 255) & ~(size_t)255;
        return p;
    };
    ushort_t* trans   = (ushort_t*)alloc((size_t)N_NODES * 256 * 2);   // 51.2 MB bf16
    float*    ah      = (float*)   alloc((size_t)N_NODES * 128 * 4);   // 51.2 MB [a|h] f32
    int*      adj     = (int*)     alloc((size_t)N_EDGES * 4);
    int*      row_ptr = (int*)     alloc((size_t)(N_NODES + 1) * 4);
    int*      cursor  = (int*)     alloc((size_t)N_NODES * 4);
    int*      deg     = (int*)     alloc((size_t)N_NODES * 4);
    int*      bsum    = (int*)     alloc(1024);
    ushort_t* B1      = (ushort_t*)alloc((size_t)6 * 16 * 4 * 16 * 8 * 2);   // 96 KB
    float*    bs1     = (float*)   alloc(256 * 4);
    ushort_t* B2      = (ushort_t*)alloc((size_t)12 * 16 * 4 * 16 * 8 * 2);  // 192 KB
    float*    bg2     = (float*)   alloc(256 * 4);
    float*    hg      = (float*)   alloc(128 * 64 * 4);

    // weight packing
    hipLaunchKernelGGL(k_pack_b1, dim3(192), dim3(256), 0, stream, We, be, B1, bs1);
    hipLaunchKernelGGL(k_pack_b2, dim3(384), dim3(256), 0, stream, W_ih, b_ih, W_hh, b_hh, B2, bg2);
    // h0
    hipLaunchKernelGGL(k_linear_in, dim3(1024), dim3(256), 0, stream, x, W_in, b_in, ah);
    // CSR build
    hipMemsetAsync(deg, 0, (size_t)N_NODES * 4, stream);
    hipLaunchKernelGGL(k_hist, dim3((N_EDGES + 255) / 256), dim3(256), 0, stream, dst, deg);
    int nblk = (N_NODES + 1023) / 1024;
    hipLaunchKernelGGL(k_scan1, dim3(nblk), dim3(256), 0, stream, deg, row_ptr, bsum, N_NODES);
    hipLaunchKernelGGL(k_scan2, dim3(1), dim3(64), 0, stream, bsum, nblk, row_ptr + N_NODES);
    hipLaunchKernelGGL(k_scan3, dim3((N_NODES + 255) / 256), dim3(256), 0, stream, row_ptr, cursor, bsum, N_NODES);
    hipLaunchKernelGGL(k_fill, dim3((N_EDGES + 255) / 256), dim3(256), 0, stream, src, dst, etype, cursor, adj);

    int gblk = (N_NODES + 127) / 128;   // 782
    for (int step = 0; step < STEPS; ++step) {
        hipLaunchKernelGGL(k_mm1, dim3(gblk), dim3(512), 0, stream, ah, B1, bs1, trans);
        hipLaunchKernelGGL(k_aggregate, dim3((N_NODES + 3) / 4), dim3(256), 0, stream,
                           row_ptr, adj, trans, ah);
        hipLaunchKernelGGL(k_mm2, dim3(gblk), dim3(512), 0, stream, ah, B2, bg2);
    }
    hipLaunchKernelGGL(k_pool, dim3(G_GRAPHS), dim3(256), 0, stream, n2g, ah, hg);
    hipLaunchKernelGGL(k_cls, dim3(G_GRAPHS), dim3(64), 0, stream, hg, W1, b1, W2, b2, out);
}

// Round 3
// 1263.288 us; speedup vs baseline: 1.2265x; 1.0821x over previous
//
#include <hip/hip_runtime.h>
#include <hip/hip_bf16.h>
#include <math.h>

#define N_NODES 100000
#define N_EDGES 1000000
#define IN_DIM 128
#define HID 64
#define NET 4
#define STEPS 5
#define G_GRAPHS 128
#define LBL 10
#define NGRP 6250        // N_NODES / 16 (exact)
#define NGRP_PAD 6256    // padded to multiple of 8 (each mm block covers 8 groups)

typedef __attribute__((ext_vector_type(8))) short short8;
typedef __attribute__((ext_vector_type(4))) float f32x4;
typedef unsigned short ushort_t;

__device__ inline ushort_t f2bf(float v) {
    __hip_bfloat16 b = __float2bfloat16(v);
    return __builtin_bit_cast(ushort_t, b);
}
__device__ inline float bf2f(ushort_t u) {
    __hip_bfloat16 b = __builtin_bit_cast(__hip_bfloat16, u);
    return __bfloat162float(b);
}

// AH layout: [group][32 blocks][16 rows(u)][8 elems(j)] shorts.
// blocks 0-7: a-hi, 8-15: h-hi, 16-23: a-lo, 24-31: h-lo.  group stride = 4096 shorts.

// ---------------- pack B1: We -> [6 slices][16 ct][4 g][16 u][8 j] bf16 ----------------
// s0,s1: Whi (k 0..63) for A-hi ; s2,s3: Whi for A-lo ; s4,s5: Wlo for A-hi
__global__ void k_pack_b1(const float* __restrict__ We, const float* __restrict__ be,
                          ushort_t* __restrict__ B1, float* __restrict__ bs1) {
    int idx = blockIdx.x * blockDim.x + threadIdx.x;
    if (idx >= 6 * 16 * 4 * 16 * 8) return;
    int j = idx & 7, u = (idx >> 3) & 15, g = (idx >> 7) & 3, ct = (idx >> 9) & 15, s = idx >> 13;
    int m = ct * 16 + u;
    int t = m >> 6, o = m & 63;
    int sk = (s < 2) ? s : (s < 4) ? (s - 2) : (s - 4);
    int k = sk * 32 + g * 8 + j;
    float val = We[t * 4096 + o * 64 + k];
    ushort_t hi = f2bf(val);
    B1[idx] = (s < 4) ? hi : f2bf(val - bf2f(hi));
    if (s == 0 && g == 0 && j == 0) bs1[m] = be[t * 64 + o];
}

// ---------------- pack B2: GRU fused weight -> [12][16][4][16][8] bf16 ----------------
// col m = q*64 + gate*16 + u ; slices 0-7: Whi (A-hi k0-127, A-lo k0-127) ; 8-11: Wlo (A-hi)
__global__ void k_pack_b2(const float* __restrict__ W_ih, const float* __restrict__ b_ih,
                          const float* __restrict__ W_hh, const float* __restrict__ b_hh,
                          ushort_t* __restrict__ B2, float* __restrict__ bg2) {
    int idx = blockIdx.x * blockDim.x + threadIdx.x;
    if (idx >= 12 * 16 * 4 * 16 * 8) return;
    int j = idx & 7, u = (idx >> 3) & 15, g = (idx >> 7) & 3, ct = (idx >> 9) & 15, s = idx >> 13;
    int m = ct * 16 + u;
    int q = m >> 6, gate = (m >> 4) & 3, c = q * 16 + (m & 15);
    int k = (s & 3) * 32 + g * 8 + j;
    float val;
    if (gate == 0)      { int jr = c;        val = (k < 64) ? W_ih[jr * 64 + k] : W_hh[jr * 64 + k - 64]; }
    else if (gate == 1) { int jr = 64 + c;   val = (k < 64) ? W_ih[jr * 64 + k] : W_hh[jr * 64 + k - 64]; }
    else if (gate == 2) { int jr = 128 + c;  val = (k < 64) ? W_ih[jr * 64 + k] : 0.f; }
    else                { int jr = 128 + c;  val = (k < 64) ? 0.f : W_hh[jr * 64 + k - 64]; }
    ushort_t hi = f2bf(val);
    B2[idx] = (s < 8) ? hi : f2bf(val - bf2f(hi));
    if (s == 0 && g == 0 && j == 0) {
        float bv;
        if (gate == 0)      bv = b_ih[c] + b_hh[c];
        else if (gate == 1) bv = b_ih[64 + c] + b_hh[64 + c];
        else if (gate == 2) bv = b_ih[128 + c];
        else                bv = b_hh[128 + c];
        bg2[m] = bv;
    }
}

// ---------------- h0 = x @ W_in.T + b_in, writes split h into AH ----------------
__global__ __launch_bounds__(256) void k_linear_in(const float* __restrict__ x,
        const float* __restrict__ W_in, const float* __restrict__ b_in,
        ushort_t* __restrict__ AH) {
    __shared__ float wl[64 * 129];
    __shared__ float xl[4 * 128];
    __shared__ float hlds[16 * 72];
    for (int i = threadIdx.x; i < 64 * 128; i += 256) {
        int o = i >> 7, k = i & 127;
        wl[o * 129 + k] = W_in[i];
    }
    int nl = threadIdx.x >> 6, o = threadIdx.x & 63;
    float bo = b_in[o];
    int grp = blockIdx.x;
    #pragma unroll
    for (int r = 0; r < 4; ++r) {
        int n = grp * 16 + r * 4 + nl;   // always < N (6250*16 == 100000)
        __syncthreads();
        xl[nl * 128 + o]      = x[(size_t)n * 128 + o];
        xl[nl * 128 + 64 + o] = x[(size_t)n * 128 + 64 + o];
        __syncthreads();
        float acc = 0.f;
        #pragma unroll 8
        for (int k = 0; k < 128; ++k)
            acc = fmaf(xl[nl * 128 + k], wl[o * 129 + k], acc);
        hlds[(r * 4 + nl) * 72 + o] = acc + bo;
    }
    __syncthreads();
    int bi = threadIdx.x >> 4, u = threadIdx.x & 15;
    int b8 = bi & 7;
    bool ishi = bi < 8;
    short8 ov;
    #pragma unroll
    for (int j = 0; j < 8; ++j) {
        float v = hlds[u * 72 + b8 * 8 + j];
        ushort_t hh = f2bf(v);
        ov[j] = ishi ? (short)hh : (short)f2bf(v - bf2f(hh));
    }
    *(short8*)&AH[((size_t)grp * 32 + (ishi ? 8 + b8 : 24 + b8)) * 128 + u * 8] = ov;
}

// ---------------- CSR build (once per call) ----------------
__global__ void k_hist(const int* __restrict__ dst, int* __restrict__ deg) {
    int e = blockIdx.x * blockDim.x + threadIdx.x;
    if (e < N_EDGES) atomicAdd(&deg[dst[e]], 1);
}

__global__ __launch_bounds__(256) void k_scan1(const int* __restrict__ deg,
        int* __restrict__ ex, int* __restrict__ bsum, int n) {
    __shared__ int ts[256];
    int base = blockIdx.x * 1024;
    int vals[4]; int s = 0;
    #pragma unroll
    for (int i = 0; i < 4; ++i) {
        int idx = base + threadIdx.x * 4 + i;
        vals[i] = (idx < n) ? deg[idx] : 0;
        s += vals[i];
    }
    ts[threadIdx.x] = s;
    __syncthreads();
    for (int off = 1; off < 256; off <<= 1) {
        int v = (threadIdx.x >= off) ? ts[threadIdx.x - off] : 0;
        __syncthreads();
        ts[threadIdx.x] += v;
        __syncthreads();
    }
    int run = (threadIdx.x == 0) ? 0 : ts[threadIdx.x - 1];
    #pragma unroll
    for (int i = 0; i < 4; ++i) {
        int idx = base + threadIdx.x * 4 + i;
        if (idx < n) ex[idx] = run;
        run += vals[i];
    }
    if (threadIdx.x == 255) bsum[blockIdx.x] = ts[255];
}

__global__ void k_scan2(int* bsum, int nb, int* row_ptr_end) {
    if (threadIdx.x == 0 && blockIdx.x == 0) {
        int run = 0;
        for (int i = 0; i < nb; ++i) { int t = bsum[i]; bsum[i] = run; run += t; }
        *row_ptr_end = run;
    }
}

__global__ void k_scan3(int* __restrict__ row_ptr, int* __restrict__ cursor,
                        const int* __restrict__ bsum, int n) {
    int i = blockIdx.x * blockDim.x + threadIdx.x;
    if (i < n) {
        int v = row_ptr[i] + bsum[i >> 10];
        row_ptr[i] = v;
        cursor[i] = v;
    }
}

__global__ void k_fill(const int* __restrict__ src, const int* __restrict__ dst,
                       const int* __restrict__ et, int* __restrict__ cursor,
                       int* __restrict__ adj) {
    int e = blockIdx.x * blockDim.x + threadIdx.x;
    if (e < N_EDGES) {
        int d = dst[e];
        int p = atomicAdd(&cursor[d], 1);
        adj[p] = src[e] | (et[e] << 20);
    }
}

// ---------------- GEMM1: trans[N,256](bf16) = split3(h) x B1, A direct from AH ----------------
__global__ __launch_bounds__(512) void k_mm1(const ushort_t* __restrict__ AH,
        const ushort_t* __restrict__ B1, const float* __restrict__ bs1,
        ushort_t* __restrict__ trans) {
    __shared__ ushort_t lds[64 * 264];   // epilogue assembly only
    int tid = threadIdx.x;
    int lane = tid & 63, wp = tid >> 6;
    int q = wp & 3, rp = wp >> 2;
    int g = lane >> 4, u = lane & 15;
    int n0 = blockIdx.x * 128;
    size_t grpbase = (size_t)(blockIdx.x * 8 + rp * 4);
    f32x4 zero = {0.f, 0.f, 0.f, 0.f};
    f32x4 acc[4][4];
    #pragma unroll
    for (int i = 0; i < 4; ++i)
        #pragma unroll
        for (int j = 0; j < 4; ++j) acc[i][j] = zero;
    const int bb1[6] = {8, 12, 24, 28, 8, 12};   // h-hi, h-lo, h-hi blocks
    #pragma unroll
    for (int s = 0; s < 6; ++s) {
        short8 bfr[4], afr[4];
        #pragma unroll
        for (int ct = 0; ct < 4; ++ct)
            bfr[ct] = *(const short8*)&B1[((size_t)(s * 16 + q * 4 + ct) * 64 + g * 16 + u) * 8];
        #pragma unroll
        for (int rt = 0; rt < 4; ++rt)
            afr[rt] = *(const short8*)&AH[((grpbase + rt) * 32 + bb1[s] + g) * 128 + u * 8];
        #pragma unroll
        for (int rt = 0; rt < 4; ++rt)
            #pragma unroll
            for (int ct = 0; ct < 4; ++ct)
                acc[rt][ct] = __builtin_amdgcn_mfma_f32_16x16x32_bf16(afr[rt], bfr[ct], acc[rt][ct], 0, 0, 0);
    }
    float bsv[4];
    #pragma unroll
    for (int ct = 0; ct < 4; ++ct) bsv[ct] = bs1[q * 64 + ct * 16 + u];
    #pragma unroll
    for (int h = 0; h < 2; ++h) {
        __syncthreads();
        if (rp == h) {
            #pragma unroll
            for (int rt = 0; rt < 4; ++rt)
                #pragma unroll
                for (int ct = 0; ct < 4; ++ct)
                    #pragma unroll
                    for (int j = 0; j < 4; ++j) {
                        int rl = rt * 16 + g * 4 + j;
                        lds[rl * 264 + q * 64 + ct * 16 + u] = f2bf(acc[rt][ct][j] + bsv[ct]);
                    }
        }
        __syncthreads();
        int rl = tid >> 3, seg = tid & 7;
        int n = n0 + h * 64 + rl;
        if (n < N_NODES) {
            #pragma unroll
            for (int i = 0; i < 4; ++i) {
                short8 v = *(const short8*)&lds[rl * 264 + seg * 32 + i * 8];
                *(short8*)&trans[(size_t)n * 256 + seg * 32 + i * 8] = v;
            }
        }
    }
}

// ---------------- GEMM2 + GRU: h = GRU(a,h) in-place in AH ----------------
__global__ __launch_bounds__(512) void k_mm2(ushort_t* __restrict__ AH,
        const ushort_t* __restrict__ B2, const float* __restrict__ bg2) {
    __shared__ ushort_t hl[128 * 136];   // h-out split: [row][hi 0..63 | lo 64..127 | pad]
    int tid = threadIdx.x;
    int lane = tid & 63, wp = tid >> 6;
    int q = wp & 3, rp = wp >> 2;
    int g = lane >> 4, u = lane & 15;
    size_t grpbase = (size_t)(blockIdx.x * 8 + rp * 4);
    f32x4 zero = {0.f, 0.f, 0.f, 0.f};
    f32x4 acc[4][4];
    #pragma unroll
    for (int i = 0; i < 4; ++i)
        #pragma unroll
        for (int j = 0; j < 4; ++j) acc[i][j] = zero;
    const int bb2[12] = {0, 4, 8, 12, 16, 20, 24, 28, 0, 4, 8, 12};
    #pragma unroll
    for (int s = 0; s < 12; ++s) {
        short8 bfr[4], afr[4];
        #pragma unroll
        for (int ct = 0; ct < 4; ++ct)
            bfr[ct] = *(const short8*)&B2[((size_t)(s * 16 + q * 4 + ct) * 64 + g * 16 + u) * 8];
        #pragma unroll
        for (int rt = 0; rt < 4; ++rt)
            afr[rt] = *(const short8*)&AH[((grpbase + rt) * 32 + bb2[s] + g) * 128 + u * 8];
        #pragma unroll
        for (int rt = 0; rt < 4; ++rt)
            #pragma unroll
            for (int ct = 0; ct < 4; ++ct)
                acc[rt][ct] = __builtin_amdgcn_mfma_f32_16x16x32_bf16(afr[rt], bfr[ct], acc[rt][ct], 0, 0, 0);
    }
    float bgv[4];
    #pragma unroll
    for (int ct = 0; ct < 4; ++ct) bgv[ct] = bg2[q * 64 + ct * 16 + u];
    int hid = q * 16 + u;
    int bhi = 8 + (hid >> 3), blo = 24 + (hid >> 3), el = hid & 7;
    #pragma unroll
    for (int rt = 0; rt < 4; ++rt) {
        size_t rbase = (grpbase + rt) * 4096;
        float ho[4];
        #pragma unroll
        for (int j = 0; j < 4; ++j) {
            int uu = g * 4 + j;
            ho[j] = bf2f(AH[rbase + bhi * 128 + uu * 8 + el])
                  + bf2f(AH[rbase + blo * 128 + uu * 8 + el]);
        }
        #pragma unroll
        for (int j = 0; j < 4; ++j) {
            float rs  = acc[rt][0][j] + bgv[0];
            float zs  = acc[rt][1][j] + bgv[1];
            float inn = acc[rt][2][j] + bgv[2];
            float hnn = acc[rt][3][j] + bgv[3];
            float r = 1.f / (1.f + __expf(-rs));
            float z = 1.f / (1.f + __expf(-zs));
            float nn = tanhf(inn + r * hnn);
            float hnew = (1.f - z) * nn + z * ho[j];
            int rl = rp * 64 + rt * 16 + g * 4 + j;
            ushort_t hh = f2bf(hnew);
            hl[rl * 136 + hid] = hh;
            hl[rl * 136 + 64 + hid] = f2bf(hnew - bf2f(hh));
        }
    }
    __syncthreads();
    // pack-out: 8 groups x 16 blocks x 16 u = 2048 short8 chunks, coalesced
    #pragma unroll
    for (int k = 0; k < 4; ++k) {
        int c = tid + k * 512;
        int gi = c >> 8, r = c & 255, bi = r >> 4, uu = r & 15;
        int row = gi * 16 + uu;
        int lofs = row * 136 + (bi < 8 ? bi * 8 : 64 + (bi - 8) * 8);
        short8 v = *(const short8*)&hl[lofs];
        int blk = (bi < 8) ? (8 + bi) : (16 + bi);   // h-hi 8..15, h-lo 24..31
        *(short8*)&AH[((size_t)(blockIdx.x * 8 + gi) * 32 + blk) * 128 + uu * 8] = v;
    }
}

// ---------------- aggregation via CSR; writes split a into AH ----------------
__global__ __launch_bounds__(256) void k_aggregate(const int* __restrict__ row_ptr,
        const int* __restrict__ adj, const ushort_t* __restrict__ trans,
        ushort_t* __restrict__ AH) {
    __shared__ float alds[16 * 72];
    int w = threadIdx.x >> 6, lane = threadIdx.x & 63;
    int grp = blockIdx.x;
    #pragma unroll
    for (int r = 0; r < 4; ++r) {
        int n = grp * 16 + r * 4 + w;
        int beg = row_ptr[n], end = row_ptr[n + 1];
        float acc = 0.f;
        for (int i = beg; i < end; ++i) {
            int pk = adj[i];
            int s = pk & 0xFFFFF;
            int et = pk >> 20;
            acc += bf2f(trans[(size_t)s * 256 + et * 64 + lane]);
        }
        alds[(r * 4 + w) * 72 + lane] = acc;
    }
    __syncthreads();
    int bi = threadIdx.x >> 4, u = threadIdx.x & 15;
    int b8 = bi & 7;
    bool ishi = bi < 8;
    short8 ov;
    #pragma unroll
    for (int j = 0; j < 8; ++j) {
        float v = alds[u * 72 + b8 * 8 + j];
        ushort_t hh = f2bf(v);
        ov[j] = ishi ? (short)hh : (short)f2bf(v - bf2f(hh));
    }
    *(short8*)&AH[((size_t)grp * 32 + (ishi ? b8 : 16 + b8)) * 128 + u * 8] = ov;
}

// ---------------- per-graph mean pooling ----------------
__global__ __launch_bounds__(256) void k_pool(const int* __restrict__ n2g,
        const ushort_t* __restrict__ AH, float* __restrict__ hg) {
    int gidx = blockIdx.x;
    int lo = 0, hi = N_NODES;
    while (lo < hi) { int mid = (lo + hi) >> 1; if (n2g[mid] < gidx) lo = mid + 1; else hi = mid; }
    int s = lo;
    hi = N_NODES;
    while (lo < hi) { int mid = (lo + hi) >> 1; if (n2g[mid] < gidx + 1) lo = mid + 1; else hi = mid; }
    int e = lo;
    int w = threadIdx.x >> 6, lane = threadIdx.x & 63;
    int bh = 8 + (lane >> 3), bl = 24 + (lane >> 3), el = lane & 7;
    float sum = 0.f;
    for (int n = s + w; n < e; n += 4) {
        size_t base = (size_t)(n >> 4) * 4096 + (size_t)(n & 15) * 8;
        sum += bf2f(AH[base + bh * 128 + el]) + bf2f(AH[base + bl * 128 + el]);
    }
    __shared__ float red[4][64];
    red[w][lane] = sum;
    __syncthreads();
    if (threadIdx.x < 64) {
        float tot = red[0][lane] + red[1][lane] + red[2][lane] + red[3][lane];
        float cnt = (float)(e - s);
        hg[gidx * 64 + lane] = tot / fmaxf(cnt, 1.f);
    }
}

// ---------------- classifier ----------------
__global__ __launch_bounds__(64) void k_cls(const float* __restrict__ hg,
        const float* __restrict__ W1, const float* __restrict__ b1,
        const float* __restrict__ W2, const float* __restrict__ b2,
        float* __restrict__ out) {
    int gidx = blockIdx.x;
    __shared__ float v[64];
    __shared__ float m[32];
    v[threadIdx.x] = hg[gidx * 64 + threadIdx.x];
    __syncthreads();
    if (threadIdx.x < 32) {
        float a = b1[threadIdx.x];
        #pragma unroll 8
        for (int k = 0; k < 64; ++k) a = fmaf(v[k], W1[threadIdx.x * 64 + k], a);
        m[threadIdx.x] = fmaxf(a, 0.f);
    }
    __syncthreads();
    if (threadIdx.x < 10) {
        float a = b2[threadIdx.x];
        #pragma unroll
        for (int j = 0; j < 32; ++j) a = fmaf(m[j], W2[threadIdx.x * 32 + j], a);
        out[gidx * 10 + threadIdx.x] = a;
    }
}

extern "C" void kernel_launch(void* const* d_in, const int* in_sizes, int n_in,
                              void* d_out, int out_size, void* d_ws, size_t ws_size,
                              hipStream_t stream) {
    const float* x    = (const float*)d_in[0];
    const int* src    = (const int*)d_in[1];
    const int* dst    = (const int*)d_in[2];
    const int* etype  = (const int*)d_in[3];
    const int* n2g    = (const int*)d_in[4];
    const float* W_in = (const float*)d_in[5];
    const float* b_in = (const float*)d_in[6];
    const float* We   = (const float*)d_in[7];
    const float* be   = (const float*)d_in[8];
    const float* W_ih = (const float*)d_in[9];
    const float* b_ih = (const float*)d_in[10];
    const float* W_hh = (const float*)d_in[11];
    const float* b_hh = (const float*)d_in[12];
    const float* W1   = (const float*)d_in[13];
    const float* b1   = (const float*)d_in[14];
    const float* W2   = (const float*)d_in[15];
    const float* b2   = (const float*)d_in[16];
    float* out = (float*)d_out;

    char* wsb = (char*)d_ws;
    size_t off = 0;
    auto alloc = [&](size_t bytes) -> void* {
        void* p = wsb + off;
        off += (bytes + 255) & ~(size_t)255;
        return p;
    };
    ushort_t* AH      = (ushort_t*)alloc((size_t)NGRP_PAD * 4096 * 2);   // 51.25 MB split [a|h]
    ushort_t* trans   = (ushort_t*)alloc((size_t)N_NODES * 256 * 2);     // 51.2 MB bf16
    int*      adj     = (int*)     alloc((size_t)N_EDGES * 4);
    int*      row_ptr = (int*)     alloc((size_t)(N_NODES + 1) * 4);
    int*      cursor  = (int*)     alloc((size_t)N_NODES * 4);
    int*      deg     = (int*)     alloc((size_t)N_NODES * 4);
    int*      bsum    = (int*)     alloc(1024);
    ushort_t* B1      = (ushort_t*)alloc((size_t)6 * 16 * 4 * 16 * 8 * 2);
    float*    bs1     = (float*)   alloc(256 * 4);
    ushort_t* B2      = (ushort_t*)alloc((size_t)12 * 16 * 4 * 16 * 8 * 2);
    float*    bg2     = (float*)   alloc(256 * 4);
    float*    hg      = (float*)   alloc(128 * 64 * 4);

    // zero padding groups (6250..6255) so mm-block 781's OOB-row reads are finite+deterministic
    hipMemsetAsync(AH + (size_t)NGRP * 4096, 0, (size_t)(NGRP_PAD - NGRP) * 4096 * 2, stream);

    hipLaunchKernelGGL(k_pack_b1, dim3(192), dim3(256), 0, stream, We, be, B1, bs1);
    hipLaunchKernelGGL(k_pack_b2, dim3(384), dim3(256), 0, stream, W_ih, b_ih, W_hh, b_hh, B2, bg2);
    hipLaunchKernelGGL(k_linear_in, dim3(NGRP), dim3(256), 0, stream, x, W_in, b_in, AH);

    hipMemsetAsync(deg, 0, (size_t)N_NODES * 4, stream);
    hipLaunchKernelGGL(k_hist, dim3((N_EDGES + 255) / 256), dim3(256), 0, stream, dst, deg);
    int nblk = (N_NODES + 1023) / 1024;
    hipLaunchKernelGGL(k_scan1, dim3(nblk), dim3(256), 0, stream, deg, row_ptr, bsum, N_NODES);
    hipLaunchKernelGGL(k_scan2, dim3(1), dim3(64), 0, stream, bsum, nblk, row_ptr + N_NODES);
    hipLaunchKernelGGL(k_scan3, dim3((N_NODES + 255) / 256), dim3(256), 0, stream, row_ptr, cursor, bsum, N_NODES);
    hipLaunchKernelGGL(k_fill, dim3((N_EDGES + 255) / 256), dim3(256), 0, stream, src, dst, etype, cursor, adj);

    int gblk = NGRP_PAD / 8;   // 782
    for (int step = 0; step < STEPS; ++step) {
        hipLaunchKernelGGL(k_mm1, dim3(gblk), dim3(512), 0, stream, AH, B1, bs1, trans);
        hipLaunchKernelGGL(k_aggregate, dim3(NGRP), dim3(256), 0, stream, row_ptr, adj, trans, AH);
        hipLaunchKernelGGL(k_mm2, dim3(gblk), dim3(512), 0, stream, AH, B2, bg2);
    }
    hipLaunchKernelGGL(k_pool, dim3(G_GRAPHS), dim3(256), 0, stream, n2g, AH, hg);
    hipLaunchKernelGGL(k_cls, dim3(G_GRAPHS), dim3(64), 0, stream, hg, W1, b1, W2, b2, out);
}

// Round 4
// 1033.331 us; speedup vs baseline: 1.4995x; 1.2225x over previous
//
#include <hip/hip_runtime.h>
#include <hip/hip_bf16.h>
#include <math.h>

#define N_NODES 100000
#define N_EDGES 1000000
#define IN_DIM 128
#define HID 64
#define NET 4
#define STEPS 5
#define G_GRAPHS 128
#define LBL 10
#define NGRP 6250        // N_NODES / 16 (exact)
#define NGRP_PAD 6256    // padded to multiple of 8 (each mm block covers 8 groups)

typedef __attribute__((ext_vector_type(8))) short short8;
typedef __attribute__((ext_vector_type(4))) float f32x4;
typedef unsigned short ushort_t;

__device__ inline ushort_t f2bf(float v) {
    __hip_bfloat16 b = __float2bfloat16(v);
    return __builtin_bit_cast(ushort_t, b);
}
__device__ inline float bf2f(ushort_t u) {
    __hip_bfloat16 b = __builtin_bit_cast(__hip_bfloat16, u);
    return __bfloat162float(b);
}

// AH layout: [group][32 blocks][16 rows(u)][8 elems(j)] shorts.
// blocks 0-7: a-hi, 8-15: h-hi, 16-23: a-lo, 24-31: h-lo.  group stride = 4096 shorts.

// ---------------- pack B1: We -> [6 slices][16 ct][4 g][16 u][8 j] bf16 ----------------
// s0,s1: Whi (k 0..63) for A-hi ; s2,s3: Whi for A-lo ; s4,s5: Wlo for A-hi
__global__ void k_pack_b1(const float* __restrict__ We, const float* __restrict__ be,
                          ushort_t* __restrict__ B1, float* __restrict__ bs1) {
    int idx = blockIdx.x * blockDim.x + threadIdx.x;
    if (idx >= 6 * 16 * 4 * 16 * 8) return;
    int j = idx & 7, u = (idx >> 3) & 15, g = (idx >> 7) & 3, ct = (idx >> 9) & 15, s = idx >> 13;
    int m = ct * 16 + u;
    int t = m >> 6, o = m & 63;
    int sk = (s < 2) ? s : (s < 4) ? (s - 2) : (s - 4);
    int k = sk * 32 + g * 8 + j;
    float val = We[t * 4096 + o * 64 + k];
    ushort_t hi = f2bf(val);
    B1[idx] = (s < 4) ? hi : f2bf(val - bf2f(hi));
    if (s == 0 && g == 0 && j == 0) bs1[m] = be[t * 64 + o];
}

// ---------------- pack B2: GRU fused weight -> [12][16][4][16][8] bf16 ----------------
// col m = q*64 + gate*16 + u ; slices 0-7: Whi (A-hi k0-127, A-lo k0-127) ; 8-11: Wlo (A-hi)
__global__ void k_pack_b2(const float* __restrict__ W_ih, const float* __restrict__ b_ih,
                          const float* __restrict__ W_hh, const float* __restrict__ b_hh,
                          ushort_t* __restrict__ B2, float* __restrict__ bg2) {
    int idx = blockIdx.x * blockDim.x + threadIdx.x;
    if (idx >= 12 * 16 * 4 * 16 * 8) return;
    int j = idx & 7, u = (idx >> 3) & 15, g = (idx >> 7) & 3, ct = (idx >> 9) & 15, s = idx >> 13;
    int m = ct * 16 + u;
    int q = m >> 6, gate = (m >> 4) & 3, c = q * 16 + (m & 15);
    int k = (s & 3) * 32 + g * 8 + j;
    float val;
    if (gate == 0)      { int jr = c;        val = (k < 64) ? W_ih[jr * 64 + k] : W_hh[jr * 64 + k - 64]; }
    else if (gate == 1) { int jr = 64 + c;   val = (k < 64) ? W_ih[jr * 64 + k] : W_hh[jr * 64 + k - 64]; }
    else if (gate == 2) { int jr = 128 + c;  val = (k < 64) ? W_ih[jr * 64 + k] : 0.f; }
    else                { int jr = 128 + c;  val = (k < 64) ? 0.f : W_hh[jr * 64 + k - 64]; }
    ushort_t hi = f2bf(val);
    B2[idx] = (s < 8) ? hi : f2bf(val - bf2f(hi));
    if (s == 0 && g == 0 && j == 0) {
        float bv;
        if (gate == 0)      bv = b_ih[c] + b_hh[c];
        else if (gate == 1) bv = b_ih[64 + c] + b_hh[64 + c];
        else if (gate == 2) bv = b_ih[128 + c];
        else                bv = b_hh[128 + c];
        bg2[m] = bv;
    }
}

// ---------------- h0 = x @ W_in.T + b_in, writes split h into AH ----------------
__global__ __launch_bounds__(256) void k_linear_in(const float* __restrict__ x,
        const float* __restrict__ W_in, const float* __restrict__ b_in,
        ushort_t* __restrict__ AH) {
    __shared__ float wl[64 * 129];
    __shared__ float xl[4 * 128];
    __shared__ float hlds[16 * 72];
    for (int i = threadIdx.x; i < 64 * 128; i += 256) {
        int o = i >> 7, k = i & 127;
        wl[o * 129 + k] = W_in[i];
    }
    int nl = threadIdx.x >> 6, o = threadIdx.x & 63;
    float bo = b_in[o];
    int grp = blockIdx.x;
    #pragma unroll
    for (int r = 0; r < 4; ++r) {
        int n = grp * 16 + r * 4 + nl;   // always < N (6250*16 == 100000)
        __syncthreads();
        xl[nl * 128 + o]      = x[(size_t)n * 128 + o];
        xl[nl * 128 + 64 + o] = x[(size_t)n * 128 + 64 + o];
        __syncthreads();
        float acc = 0.f;
        #pragma unroll 8
        for (int k = 0; k < 128; ++k)
            acc = fmaf(xl[nl * 128 + k], wl[o * 129 + k], acc);
        hlds[(r * 4 + nl) * 72 + o] = acc + bo;
    }
    __syncthreads();
    int bi = threadIdx.x >> 4, u = threadIdx.x & 15;
    int b8 = bi & 7;
    bool ishi = bi < 8;
    short8 ov;
    #pragma unroll
    for (int j = 0; j < 8; ++j) {
        float v = hlds[u * 72 + b8 * 8 + j];
        ushort_t hh = f2bf(v);
        ov[j] = ishi ? (short)hh : (short)f2bf(v - bf2f(hh));
    }
    *(short8*)&AH[((size_t)grp * 32 + (ishi ? 8 + b8 : 24 + b8)) * 128 + u * 8] = ov;
}

// ---------------- CSR build (once per call) ----------------
__global__ void k_hist(const int* __restrict__ dst, int* __restrict__ deg) {
    int e = blockIdx.x * blockDim.x + threadIdx.x;
    if (e < N_EDGES) atomicAdd(&deg[dst[e]], 1);
}

__global__ __launch_bounds__(256) void k_scan1(const int* __restrict__ deg,
        int* __restrict__ ex, int* __restrict__ bsum, int n) {
    __shared__ int ts[256];
    int base = blockIdx.x * 1024;
    int vals[4]; int s = 0;
    #pragma unroll
    for (int i = 0; i < 4; ++i) {
        int idx = base + threadIdx.x * 4 + i;
        vals[i] = (idx < n) ? deg[idx] : 0;
        s += vals[i];
    }
    ts[threadIdx.x] = s;
    __syncthreads();
    for (int off = 1; off < 256; off <<= 1) {
        int v = (threadIdx.x >= off) ? ts[threadIdx.x - off] : 0;
        __syncthreads();
        ts[threadIdx.x] += v;
        __syncthreads();
    }
    int run = (threadIdx.x == 0) ? 0 : ts[threadIdx.x - 1];
    #pragma unroll
    for (int i = 0; i < 4; ++i) {
        int idx = base + threadIdx.x * 4 + i;
        if (idx < n) ex[idx] = run;
        run += vals[i];
    }
    if (threadIdx.x == 255) bsum[blockIdx.x] = ts[255];
}

__global__ void k_scan2(int* bsum, int nb, int* row_ptr_end) {
    if (threadIdx.x == 0 && blockIdx.x == 0) {
        int run = 0;
        for (int i = 0; i < nb; ++i) { int t = bsum[i]; bsum[i] = run; run += t; }
        *row_ptr_end = run;
    }
}

__global__ void k_scan3(int* __restrict__ row_ptr, int* __restrict__ cursor,
                        const int* __restrict__ bsum, int n) {
    int i = blockIdx.x * blockDim.x + threadIdx.x;
    if (i < n) {
        int v = row_ptr[i] + bsum[i >> 10];
        row_ptr[i] = v;
        cursor[i] = v;
    }
}

__global__ void k_fill(const int* __restrict__ src, const int* __restrict__ dst,
                       const int* __restrict__ et, int* __restrict__ cursor,
                       int* __restrict__ adj) {
    int e = blockIdx.x * blockDim.x + threadIdx.x;
    if (e < N_EDGES) {
        int d = dst[e];
        int p = atomicAdd(&cursor[d], 1);
        adj[p] = src[e] | (et[e] << 20);
    }
}

// ---------------- GEMM1: trans[N,256](bf16) = split3(h) x B1, A direct from AH ----------------
__global__ __launch_bounds__(512) void k_mm1(const ushort_t* __restrict__ AH,
        const ushort_t* __restrict__ B1, const float* __restrict__ bs1,
        ushort_t* __restrict__ trans) {
    __shared__ ushort_t lds[64 * 264];   // epilogue assembly only
    int tid = threadIdx.x;
    int lane = tid & 63, wp = tid >> 6;
    int q = wp & 3, rp = wp >> 2;
    int g = lane >> 4, u = lane & 15;
    int n0 = blockIdx.x * 128;
    size_t grpbase = (size_t)(blockIdx.x * 8 + rp * 4);
    f32x4 zero = {0.f, 0.f, 0.f, 0.f};
    f32x4 acc[4][4];
    #pragma unroll
    for (int i = 0; i < 4; ++i)
        #pragma unroll
        for (int j = 0; j < 4; ++j) acc[i][j] = zero;
    const int bb1[6] = {8, 12, 24, 28, 8, 12};   // h-hi, h-lo, h-hi blocks
    #pragma unroll
    for (int s = 0; s < 6; ++s) {
        short8 bfr[4], afr[4];
        #pragma unroll
        for (int ct = 0; ct < 4; ++ct)
            bfr[ct] = *(const short8*)&B1[((size_t)(s * 16 + q * 4 + ct) * 64 + g * 16 + u) * 8];
        #pragma unroll
        for (int rt = 0; rt < 4; ++rt)
            afr[rt] = *(const short8*)&AH[((grpbase + rt) * 32 + bb1[s] + g) * 128 + u * 8];
        #pragma unroll
        for (int rt = 0; rt < 4; ++rt)
            #pragma unroll
            for (int ct = 0; ct < 4; ++ct)
                acc[rt][ct] = __builtin_amdgcn_mfma_f32_16x16x32_bf16(afr[rt], bfr[ct], acc[rt][ct], 0, 0, 0);
    }
    float bsv[4];
    #pragma unroll
    for (int ct = 0; ct < 4; ++ct) bsv[ct] = bs1[q * 64 + ct * 16 + u];
    #pragma unroll
    for (int h = 0; h < 2; ++h) {
        __syncthreads();
        if (rp == h) {
            #pragma unroll
            for (int rt = 0; rt < 4; ++rt)
                #pragma unroll
                for (int ct = 0; ct < 4; ++ct)
                    #pragma unroll
                    for (int j = 0; j < 4; ++j) {
                        int rl = rt * 16 + g * 4 + j;
                        lds[rl * 264 + q * 64 + ct * 16 + u] = f2bf(acc[rt][ct][j] + bsv[ct]);
                    }
        }
        __syncthreads();
        int rl = tid >> 3, seg = tid & 7;
        int n = n0 + h * 64 + rl;
        if (n < N_NODES) {
            #pragma unroll
            for (int i = 0; i < 4; ++i) {
                short8 v = *(const short8*)&lds[rl * 264 + seg * 32 + i * 8];
                *(short8*)&trans[(size_t)n * 256 + seg * 32 + i * 8] = v;
            }
        }
    }
}

// ---------------- GEMM2 + GRU: h = GRU(a,h) in-place in AH ----------------
__global__ __launch_bounds__(512) void k_mm2(ushort_t* __restrict__ AH,
        const ushort_t* __restrict__ B2, const float* __restrict__ bg2) {
    __shared__ ushort_t hl[128 * 136];   // h-out split: [row][hi 0..63 | lo 64..127 | pad]
    int tid = threadIdx.x;
    int lane = tid & 63, wp = tid >> 6;
    int q = wp & 3, rp = wp >> 2;
    int g = lane >> 4, u = lane & 15;
    size_t grpbase = (size_t)(blockIdx.x * 8 + rp * 4);
    f32x4 zero = {0.f, 0.f, 0.f, 0.f};
    f32x4 acc[4][4];
    #pragma unroll
    for (int i = 0; i < 4; ++i)
        #pragma unroll
        for (int j = 0; j < 4; ++j) acc[i][j] = zero;
    const int bb2[12] = {0, 4, 8, 12, 16, 20, 24, 28, 0, 4, 8, 12};
    #pragma unroll
    for (int s = 0; s < 12; ++s) {
        short8 bfr[4], afr[4];
        #pragma unroll
        for (int ct = 0; ct < 4; ++ct)
            bfr[ct] = *(const short8*)&B2[((size_t)(s * 16 + q * 4 + ct) * 64 + g * 16 + u) * 8];
        #pragma unroll
        for (int rt = 0; rt < 4; ++rt)
            afr[rt] = *(const short8*)&AH[((grpbase + rt) * 32 + bb2[s] + g) * 128 + u * 8];
        #pragma unroll
        for (int rt = 0; rt < 4; ++rt)
            #pragma unroll
            for (int ct = 0; ct < 4; ++ct)
                acc[rt][ct] = __builtin_amdgcn_mfma_f32_16x16x32_bf16(afr[rt], bfr[ct], acc[rt][ct], 0, 0, 0);
    }
    float bgv[4];
    #pragma unroll
    for (int ct = 0; ct < 4; ++ct) bgv[ct] = bg2[q * 64 + ct * 16 + u];
    int hid = q * 16 + u;
    int bhi = 8 + (hid >> 3), blo = 24 + (hid >> 3), el = hid & 7;
    #pragma unroll
    for (int rt = 0; rt < 4; ++rt) {
        size_t rbase = (grpbase + rt) * 4096;
        float ho[4];
        #pragma unroll
        for (int j = 0; j < 4; ++j) {
            int uu = g * 4 + j;
            ho[j] = bf2f(AH[rbase + bhi * 128 + uu * 8 + el])
                  + bf2f(AH[rbase + blo * 128 + uu * 8 + el]);
        }
        #pragma unroll
        for (int j = 0; j < 4; ++j) {
            float rs  = acc[rt][0][j] + bgv[0];
            float zs  = acc[rt][1][j] + bgv[1];
            float inn = acc[rt][2][j] + bgv[2];
            float hnn = acc[rt][3][j] + bgv[3];
            float r = 1.f / (1.f + __expf(-rs));
            float z = 1.f / (1.f + __expf(-zs));
            float nn = tanhf(inn + r * hnn);
            float hnew = (1.f - z) * nn + z * ho[j];
            int rl = rp * 64 + rt * 16 + g * 4 + j;
            ushort_t hh = f2bf(hnew);
            hl[rl * 136 + hid] = hh;
            hl[rl * 136 + 64 + hid] = f2bf(hnew - bf2f(hh));
        }
    }
    __syncthreads();
    // pack-out: 8 groups x 16 blocks x 16 u = 2048 short8 chunks, coalesced
    #pragma unroll
    for (int k = 0; k < 4; ++k) {
        int c = tid + k * 512;
        int gi = c >> 8, r = c & 255, bi = r >> 4, uu = r & 15;
        int row = gi * 16 + uu;
        int lofs = row * 136 + (bi < 8 ? bi * 8 : 64 + (bi - 8) * 8);
        short8 v = *(const short8*)&hl[lofs];
        int blk = (bi < 8) ? (8 + bi) : (16 + bi);   // h-hi 8..15, h-lo 24..31
        *(short8*)&AH[((size_t)(blockIdx.x * 8 + gi) * 32 + blk) * 128 + uu * 8] = v;
    }
}

// ---------------- aggregation via CSR; 1 node per wave, unroll-4 MLP ----------------
__global__ __launch_bounds__(1024) void k_aggregate(const int* __restrict__ row_ptr,
        const int* __restrict__ adj, const ushort_t* __restrict__ trans,
        ushort_t* __restrict__ AH) {
    __shared__ float alds[16 * 72];
    int w = threadIdx.x >> 6, lane = threadIdx.x & 63;
    int grp = blockIdx.x;
    int n = grp * 16 + w;          // always < N_NODES (6250*16 == 100000)
    int beg = row_ptr[n], end = row_ptr[n + 1];
    float a0 = 0.f, a1 = 0.f, a2 = 0.f, a3 = 0.f;
    int i = beg;
    for (; i + 4 <= end; i += 4) {
        int pk0 = adj[i], pk1 = adj[i + 1], pk2 = adj[i + 2], pk3 = adj[i + 3];
        ushort_t v0 = trans[(size_t)(pk0 & 0xFFFFF) * 256 + (pk0 >> 20) * 64 + lane];
        ushort_t v1 = trans[(size_t)(pk1 & 0xFFFFF) * 256 + (pk1 >> 20) * 64 + lane];
        ushort_t v2 = trans[(size_t)(pk2 & 0xFFFFF) * 256 + (pk2 >> 20) * 64 + lane];
        ushort_t v3 = trans[(size_t)(pk3 & 0xFFFFF) * 256 + (pk3 >> 20) * 64 + lane];
        a0 += bf2f(v0); a1 += bf2f(v1); a2 += bf2f(v2); a3 += bf2f(v3);
    }
    for (; i < end; ++i) {
        int pk = adj[i];
        a0 += bf2f(trans[(size_t)(pk & 0xFFFFF) * 256 + (pk >> 20) * 64 + lane]);
    }
    alds[w * 72 + lane] = (a0 + a1) + (a2 + a3);
    __syncthreads();
    if (threadIdx.x < 256) {
        int bi = threadIdx.x >> 4, u = threadIdx.x & 15;
        int b8 = bi & 7;
        bool ishi = bi < 8;
        short8 ov;
        #pragma unroll
        for (int j = 0; j < 8; ++j) {
            float v = alds[u * 72 + b8 * 8 + j];
            ushort_t hh = f2bf(v);
            ov[j] = ishi ? (short)hh : (short)f2bf(v - bf2f(hh));
        }
        *(short8*)&AH[((size_t)grp * 32 + (ishi ? b8 : 16 + b8)) * 128 + u * 8] = ov;
    }
}

// ---------------- per-graph mean pooling ----------------
__global__ __launch_bounds__(256) void k_pool(const int* __restrict__ n2g,
        const ushort_t* __restrict__ AH, float* __restrict__ hg) {
    int gidx = blockIdx.x;
    int lo = 0, hi = N_NODES;
    while (lo < hi) { int mid = (lo + hi) >> 1; if (n2g[mid] < gidx) lo = mid + 1; else hi = mid; }
    int s = lo;
    hi = N_NODES;
    while (lo < hi) { int mid = (lo + hi) >> 1; if (n2g[mid] < gidx + 1) lo = mid + 1; else hi = mid; }
    int e = lo;
    int w = threadIdx.x >> 6, lane = threadIdx.x & 63;
    int bh = 8 + (lane >> 3), bl = 24 + (lane >> 3), el = lane & 7;
    float sum = 0.f;
    for (int n = s + w; n < e; n += 4) {
        size_t base = (size_t)(n >> 4) * 4096 + (size_t)(n & 15) * 8;
        sum += bf2f(AH[base + bh * 128 + el]) + bf2f(AH[base + bl * 128 + el]);
    }
    __shared__ float red[4][64];
    red[w][lane] = sum;
    __syncthreads();
    if (threadIdx.x < 64) {
        float tot = red[0][lane] + red[1][lane] + red[2][lane] + red[3][lane];
        float cnt = (float)(e - s);
        hg[gidx * 64 + lane] = tot / fmaxf(cnt, 1.f);
    }
}

// ---------------- classifier ----------------
__global__ __launch_bounds__(64) void k_cls(const float* __restrict__ hg,
        const float* __restrict__ W1, const float* __restrict__ b1,
        const float* __restrict__ W2, const float* __restrict__ b2,
        float* __restrict__ out) {
    int gidx = blockIdx.x;
    __shared__ float v[64];
    __shared__ float m[32];
    v[threadIdx.x] = hg[gidx * 64 + threadIdx.x];
    __syncthreads();
    if (threadIdx.x < 32) {
        float a = b1[threadIdx.x];
        #pragma unroll 8
        for (int k = 0; k < 64; ++k) a = fmaf(v[k], W1[threadIdx.x * 64 + k], a);
        m[threadIdx.x] = fmaxf(a, 0.f);
    }
    __syncthreads();
    if (threadIdx.x < 10) {
        float a = b2[threadIdx.x];
        #pragma unroll
        for (int j = 0; j < 32; ++j) a = fmaf(m[j], W2[threadIdx.x * 32 + j], a);
        out[gidx * 10 + threadIdx.x] = a;
    }
}

extern "C" void kernel_launch(void* const* d_in, const int* in_sizes, int n_in,
                              void* d_out, int out_size, void* d_ws, size_t ws_size,
                              hipStream_t stream) {
    const float* x    = (const float*)d_in[0];
    const int* src    = (const int*)d_in[1];
    const int* dst    = (const int*)d_in[2];
    const int* etype  = (const int*)d_in[3];
    const int* n2g    = (const int*)d_in[4];
    const float* W_in = (const float*)d_in[5];
    const float* b_in = (const float*)d_in[6];
    const float* We   = (const float*)d_in[7];
    const float* be   = (const float*)d_in[8];
    const float* W_ih = (const float*)d_in[9];
    const float* b_ih = (const float*)d_in[10];
    const float* W_hh = (const float*)d_in[11];
    const float* b_hh = (const float*)d_in[12];
    const float* W1   = (const float*)d_in[13];
    const float* b1   = (const float*)d_in[14];
    const float* W2   = (const float*)d_in[15];
    const float* b2   = (const float*)d_in[16];
    float* out = (float*)d_out;

    char* wsb = (char*)d_ws;
    size_t off = 0;
    auto alloc = [&](size_t bytes) -> void* {
        void* p = wsb + off;
        off += (bytes + 255) & ~(size_t)255;
        return p;
    };
    ushort_t* AH      = (ushort_t*)alloc((size_t)NGRP_PAD * 4096 * 2);   // 51.25 MB split [a|h]
    ushort_t* trans   = (ushort_t*)alloc((size_t)N_NODES * 256 * 2);     // 51.2 MB bf16
    int*      adj     = (int*)     alloc((size_t)N_EDGES * 4);
    int*      row_ptr = (int*)     alloc((size_t)(N_NODES + 1) * 4);
    int*      cursor  = (int*)     alloc((size_t)N_NODES * 4);
    int*      deg     = (int*)     alloc((size_t)N_NODES * 4);
    int*      bsum    = (int*)     alloc(1024);
    ushort_t* B1      = (ushort_t*)alloc((size_t)6 * 16 * 4 * 16 * 8 * 2);
    float*    bs1     = (float*)   alloc(256 * 4);
    ushort_t* B2      = (ushort_t*)alloc((size_t)12 * 16 * 4 * 16 * 8 * 2);
    float*    bg2     = (float*)   alloc(256 * 4);
    float*    hg      = (float*)   alloc(128 * 64 * 4);

    // zero padding groups (6250..6255) so mm-block 781's OOB-row reads are finite+deterministic
    hipMemsetAsync(AH + (size_t)NGRP * 4096, 0, (size_t)(NGRP_PAD - NGRP) * 4096 * 2, stream);

    hipLaunchKernelGGL(k_pack_b1, dim3(192), dim3(256), 0, stream, We, be, B1, bs1);
    hipLaunchKernelGGL(k_pack_b2, dim3(384), dim3(256), 0, stream, W_ih, b_ih, W_hh, b_hh, B2, bg2);
    hipLaunchKernelGGL(k_linear_in, dim3(NGRP), dim3(256), 0, stream, x, W_in, b_in, AH);

    hipMemsetAsync(deg, 0, (size_t)N_NODES * 4, stream);
    hipLaunchKernelGGL(k_hist, dim3((N_EDGES + 255) / 256), dim3(256), 0, stream, dst, deg);
    int nblk = (N_NODES + 1023) / 1024;
    hipLaunchKernelGGL(k_scan1, dim3(nblk), dim3(256), 0, stream, deg, row_ptr, bsum, N_NODES);
    hipLaunchKernelGGL(k_scan2, dim3(1), dim3(64), 0, stream, bsum, nblk, row_ptr + N_NODES);
    hipLaunchKernelGGL(k_scan3, dim3((N_NODES + 255) / 256), dim3(256), 0, stream, row_ptr, cursor, bsum, N_NODES);
    hipLaunchKernelGGL(k_fill, dim3((N_EDGES + 255) / 256), dim3(256), 0, stream, src, dst, etype, cursor, adj);

    int gblk = NGRP_PAD / 8;   // 782
    for (int step = 0; step < STEPS; ++step) {
        hipLaunchKernelGGL(k_mm1, dim3(gblk), dim3(512), 0, stream, AH, B1, bs1, trans);
        hipLaunchKernelGGL(k_aggregate, dim3(NGRP), dim3(1024), 0, stream, row_ptr, adj, trans, AH);
        hipLaunchKernelGGL(k_mm2, dim3(gblk), dim3(512), 0, stream, AH, B2, bg2);
    }
    hipLaunchKernelGGL(k_pool, dim3(G_GRAPHS), dim3(256), 0, stream, n2g, AH, hg);
    hipLaunchKernelGGL(k_cls, dim3(G_GRAPHS), dim3(64), 0, stream, hg, W1, b1, W2, b2, out);
}

// Round 5
// 950.923 us; speedup vs baseline: 1.6294x; 1.0867x over previous
//
#include <hip/hip_runtime.h>
#include <hip/hip_bf16.h>
#include <math.h>

#define N_NODES 100000
#define N_EDGES 1000000
#define IN_DIM 128
#define HID 64
#define NET 4
#define STEPS 5
#define G_GRAPHS 128
#define LBL 10
#define NGRP 6250        // N_NODES / 16 (exact)
#define NGRP_PAD 6256    // padded to multiple of 8 (each mm block covers 8 groups)

typedef __attribute__((ext_vector_type(8))) short short8;
typedef __attribute__((ext_vector_type(4))) float f32x4;
typedef unsigned short ushort_t;

__device__ inline ushort_t f2bf(float v) {
    __hip_bfloat16 b = __float2bfloat16(v);
    return __builtin_bit_cast(ushort_t, b);
}
__device__ inline float bf2f(ushort_t u) {
    __hip_bfloat16 b = __builtin_bit_cast(__hip_bfloat16, u);
    return __bfloat162float(b);
}

// AH layout: [group][32 blocks][16 rows(u)][8 elems(j)] shorts.
// blocks 0-7: a-hi, 8-15: h-hi, 16-23: a-lo, 24-31: h-lo.  group stride = 4096 shorts.

// ---------------- pack B1: We -> [6 slices][16 ct][4 g][16 u][8 j] bf16 ----------------
// s0,s1: Whi (k 0..63) for A-hi ; s2,s3: Whi for A-lo ; s4,s5: Wlo for A-hi
__global__ void k_pack_b1(const float* __restrict__ We, const float* __restrict__ be,
                          ushort_t* __restrict__ B1, float* __restrict__ bs1) {
    int idx = blockIdx.x * blockDim.x + threadIdx.x;
    if (idx >= 6 * 16 * 4 * 16 * 8) return;
    int j = idx & 7, u = (idx >> 3) & 15, g = (idx >> 7) & 3, ct = (idx >> 9) & 15, s = idx >> 13;
    int m = ct * 16 + u;
    int t = m >> 6, o = m & 63;
    int sk = (s < 2) ? s : (s < 4) ? (s - 2) : (s - 4);
    int k = sk * 32 + g * 8 + j;
    float val = We[t * 4096 + o * 64 + k];
    ushort_t hi = f2bf(val);
    B1[idx] = (s < 4) ? hi : f2bf(val - bf2f(hi));
    if (s == 0 && g == 0 && j == 0) bs1[m] = be[t * 64 + o];
}

// ---------------- pack B2: GRU fused weight -> [12][16][4][16][8] bf16 ----------------
// col m = q*64 + gate*16 + u ; slices 0-7: Whi (A-hi k0-127, A-lo k0-127) ; 8-11: Wlo (A-hi)
__global__ void k_pack_b2(const float* __restrict__ W_ih, const float* __restrict__ b_ih,
                          const float* __restrict__ W_hh, const float* __restrict__ b_hh,
                          ushort_t* __restrict__ B2, float* __restrict__ bg2) {
    int idx = blockIdx.x * blockDim.x + threadIdx.x;
    if (idx >= 12 * 16 * 4 * 16 * 8) return;
    int j = idx & 7, u = (idx >> 3) & 15, g = (idx >> 7) & 3, ct = (idx >> 9) & 15, s = idx >> 13;
    int m = ct * 16 + u;
    int q = m >> 6, gate = (m >> 4) & 3, c = q * 16 + (m & 15);
    int k = (s & 3) * 32 + g * 8 + j;
    float val;
    if (gate == 0)      { int jr = c;        val = (k < 64) ? W_ih[jr * 64 + k] : W_hh[jr * 64 + k - 64]; }
    else if (gate == 1) { int jr = 64 + c;   val = (k < 64) ? W_ih[jr * 64 + k] : W_hh[jr * 64 + k - 64]; }
    else if (gate == 2) { int jr = 128 + c;  val = (k < 64) ? W_ih[jr * 64 + k] : 0.f; }
    else                { int jr = 128 + c;  val = (k < 64) ? 0.f : W_hh[jr * 64 + k - 64]; }
    ushort_t hi = f2bf(val);
    B2[idx] = (s < 8) ? hi : f2bf(val - bf2f(hi));
    if (s == 0 && g == 0 && j == 0) {
        float bv;
        if (gate == 0)      bv = b_ih[c] + b_hh[c];
        else if (gate == 1) bv = b_ih[64 + c] + b_hh[64 + c];
        else if (gate == 2) bv = b_ih[128 + c];
        else                bv = b_hh[128 + c];
        bg2[m] = bv;
    }
}

// ---------------- pack BIN: W_in -> [12 slices][4 ct][64 lane][8 j] bf16 ----------------
// slices 0-3: Whi (for Xhi), 4-7: Whi (for Xlo), 8-11: Wlo (for Xhi); k = (s&3)*32 + g*8 + j
__global__ void k_pack_bin(const float* __restrict__ W_in, ushort_t* __restrict__ BIN) {
    int idx = blockIdx.x * blockDim.x + threadIdx.x; // 12*4*64*8 = 24576
    if (idx >= 24576) return;
    int j = idx & 7, lu = (idx >> 3) & 63, ct = (idx >> 9) & 3, s = idx >> 11;
    int g = lu >> 4, u = lu & 15;
    int m = ct * 16 + u;
    int k = (s & 3) * 32 + g * 8 + j;
    float val = W_in[m * 128 + k];
    ushort_t hi = f2bf(val);
    BIN[idx] = (s < 8) ? hi : f2bf(val - bf2f(hi));
}

// ---------------- h0 = x @ W_in.T + b_in via MFMA, writes split h into AH ----------------
// 256 threads = 4 waves; each wave owns one 16-row group; A-frags direct from global x.
__global__ __launch_bounds__(256) void k_linear_in(const float* __restrict__ x,
        const ushort_t* __restrict__ BIN, const float* __restrict__ b_in,
        ushort_t* __restrict__ AH) {
    __shared__ float hlds[4][16 * 68];
    int tid = threadIdx.x;
    int lane = tid & 63, wp = tid >> 6;
    int g = lane >> 4, u = lane & 15;
    int grp = blockIdx.x * 4 + wp;
    bool ok = grp < NGRP;
    int row = ok ? (grp * 16 + u) : 0;
    // load x row chunk (32 B/lane/ks; a wave covers 16 rows x 128 B contiguous), split hi/lo
    short8 xhi[4], xlo[4];
    #pragma unroll
    for (int ks = 0; ks < 4; ++ks) {
        const float* xp = &x[(size_t)row * 128 + ks * 32 + g * 8];
        float4 v0 = ok ? *(const float4*)xp : make_float4(0.f, 0.f, 0.f, 0.f);
        float4 v1 = ok ? *(const float4*)(xp + 4) : make_float4(0.f, 0.f, 0.f, 0.f);
        float vv[8] = {v0.x, v0.y, v0.z, v0.w, v1.x, v1.y, v1.z, v1.w};
        #pragma unroll
        for (int j = 0; j < 8; ++j) {
            ushort_t hh = f2bf(vv[j]);
            xhi[ks][j] = (short)hh;
            xlo[ks][j] = (short)f2bf(vv[j] - bf2f(hh));
        }
    }
    f32x4 zero = {0.f, 0.f, 0.f, 0.f};
    f32x4 acc[4] = {zero, zero, zero, zero};
    #pragma unroll
    for (int s = 0; s < 12; ++s) {
        int ks = s & 3;
        short8 af = (s < 4) ? xhi[ks] : (s < 8) ? xlo[ks] : xhi[ks];
        #pragma unroll
        for (int ct = 0; ct < 4; ++ct) {
            short8 bf = *(const short8*)&BIN[((size_t)(s * 4 + ct) * 64 + lane) * 8];
            acc[ct] = __builtin_amdgcn_mfma_f32_16x16x32_bf16(af, bf, acc[ct], 0, 0, 0);
        }
    }
    // epilogue: transpose via per-wave LDS, split hi/lo, write h blocks
    #pragma unroll
    for (int ct = 0; ct < 4; ++ct) {
        float bo = b_in[ct * 16 + u];
        #pragma unroll
        for (int j = 0; j < 4; ++j)
            hlds[wp][(g * 4 + j) * 68 + ct * 16 + u] = acc[ct][j] + bo;
    }
    __syncthreads();
    #pragma unroll
    for (int k = 0; k < 4; ++k) {
        int bi = g + 4 * k;      // 0..15
        short8 ov;
        #pragma unroll
        for (int j = 0; j < 8; ++j) {
            float v = hlds[wp][u * 68 + (bi & 7) * 8 + j];
            ushort_t hh = f2bf(v);
            ov[j] = (bi < 8) ? (short)hh : (short)f2bf(v - bf2f(hh));
        }
        int blk = (bi < 8) ? (8 + bi) : (24 + (bi - 8));
        if (ok) *(short8*)&AH[((size_t)grp * 32 + blk) * 128 + u * 8] = ov;
    }
}

// ---------------- CSR build (once per call) ----------------
__global__ void k_hist(const int* __restrict__ dst, int* __restrict__ deg) {
    int e = blockIdx.x * blockDim.x + threadIdx.x;
    if (e < N_EDGES) atomicAdd(&deg[dst[e]], 1);
}

__global__ __launch_bounds__(256) void k_scan1(const int* __restrict__ deg,
        int* __restrict__ ex, int* __restrict__ bsum, int n) {
    __shared__ int ts[256];
    int base = blockIdx.x * 1024;
    int vals[4]; int s = 0;
    #pragma unroll
    for (int i = 0; i < 4; ++i) {
        int idx = base + threadIdx.x * 4 + i;
        vals[i] = (idx < n) ? deg[idx] : 0;
        s += vals[i];
    }
    ts[threadIdx.x] = s;
    __syncthreads();
    for (int off = 1; off < 256; off <<= 1) {
        int v = (threadIdx.x >= off) ? ts[threadIdx.x - off] : 0;
        __syncthreads();
        ts[threadIdx.x] += v;
        __syncthreads();
    }
    int run = (threadIdx.x == 0) ? 0 : ts[threadIdx.x - 1];
    #pragma unroll
    for (int i = 0; i < 4; ++i) {
        int idx = base + threadIdx.x * 4 + i;
        if (idx < n) ex[idx] = run;
        run += vals[i];
    }
    if (threadIdx.x == 255) bsum[blockIdx.x] = ts[255];
}

__global__ void k_scan2(int* bsum, int nb, int* row_ptr_end) {
    if (threadIdx.x == 0 && blockIdx.x == 0) {
        int run = 0;
        for (int i = 0; i < nb; ++i) { int t = bsum[i]; bsum[i] = run; run += t; }
        *row_ptr_end = run;
    }
}

__global__ void k_scan3(int* __restrict__ row_ptr, int* __restrict__ cursor,
                        const int* __restrict__ bsum, int n) {
    int i = blockIdx.x * blockDim.x + threadIdx.x;
    if (i < n) {
        int v = row_ptr[i] + bsum[i >> 10];
        row_ptr[i] = v;
        cursor[i] = v;
    }
}

__global__ void k_fill(const int* __restrict__ src, const int* __restrict__ dst,
                       const int* __restrict__ et, int* __restrict__ cursor,
                       int* __restrict__ adj) {
    int e = blockIdx.x * blockDim.x + threadIdx.x;
    if (e < N_EDGES) {
        int d = dst[e];
        int p = atomicAdd(&cursor[d], 1);
        adj[p] = src[e] | (et[e] << 20);
    }
}

// ---------------- GEMM1: trans[N,256](bf16) = split3(h) x B1, A direct from AH ----------------
__global__ __launch_bounds__(512) void k_mm1(const ushort_t* __restrict__ AH,
        const ushort_t* __restrict__ B1, const float* __restrict__ bs1,
        ushort_t* __restrict__ trans) {
    __shared__ ushort_t lds[64 * 264];   // epilogue assembly only
    int tid = threadIdx.x;
    int lane = tid & 63, wp = tid >> 6;
    int q = wp & 3, rp = wp >> 2;
    int g = lane >> 4, u = lane & 15;
    int n0 = blockIdx.x * 128;
    size_t grpbase = (size_t)(blockIdx.x * 8 + rp * 4);
    f32x4 zero = {0.f, 0.f, 0.f, 0.f};
    f32x4 acc[4][4];
    #pragma unroll
    for (int i = 0; i < 4; ++i)
        #pragma unroll
        for (int j = 0; j < 4; ++j) acc[i][j] = zero;
    const int bb1[6] = {8, 12, 24, 28, 8, 12};   // h-hi, h-lo, h-hi blocks
    #pragma unroll
    for (int s = 0; s < 6; ++s) {
        short8 bfr[4], afr[4];
        #pragma unroll
        for (int ct = 0; ct < 4; ++ct)
            bfr[ct] = *(const short8*)&B1[((size_t)(s * 16 + q * 4 + ct) * 64 + g * 16 + u) * 8];
        #pragma unroll
        for (int rt = 0; rt < 4; ++rt)
            afr[rt] = *(const short8*)&AH[((grpbase + rt) * 32 + bb1[s] + g) * 128 + u * 8];
        #pragma unroll
        for (int rt = 0; rt < 4; ++rt)
            #pragma unroll
            for (int ct = 0; ct < 4; ++ct)
                acc[rt][ct] = __builtin_amdgcn_mfma_f32_16x16x32_bf16(afr[rt], bfr[ct], acc[rt][ct], 0, 0, 0);
    }
    float bsv[4];
    #pragma unroll
    for (int ct = 0; ct < 4; ++ct) bsv[ct] = bs1[q * 64 + ct * 16 + u];
    #pragma unroll
    for (int h = 0; h < 2; ++h) {
        __syncthreads();
        if (rp == h) {
            #pragma unroll
            for (int rt = 0; rt < 4; ++rt)
                #pragma unroll
                for (int ct = 0; ct < 4; ++ct)
                    #pragma unroll
                    for (int j = 0; j < 4; ++j) {
                        int rl = rt * 16 + g * 4 + j;
                        lds[rl * 264 + q * 64 + ct * 16 + u] = f2bf(acc[rt][ct][j] + bsv[ct]);
                    }
        }
        __syncthreads();
        int rl = tid >> 3, seg = tid & 7;
        int n = n0 + h * 64 + rl;
        if (n < N_NODES) {
            #pragma unroll
            for (int i = 0; i < 4; ++i) {
                short8 v = *(const short8*)&lds[rl * 264 + seg * 32 + i * 8];
                *(short8*)&trans[(size_t)n * 256 + seg * 32 + i * 8] = v;
            }
        }
    }
}

// ---------------- GEMM2 + GRU: h = GRU(a,h) in-place in AH ----------------
__global__ __launch_bounds__(512) void k_mm2(ushort_t* __restrict__ AH,
        const ushort_t* __restrict__ B2, const float* __restrict__ bg2) {
    __shared__ ushort_t hl[128 * 136];   // h-out split: [row][hi 0..63 | lo 64..127 | pad]
    int tid = threadIdx.x;
    int lane = tid & 63, wp = tid >> 6;
    int q = wp & 3, rp = wp >> 2;
    int g = lane >> 4, u = lane & 15;
    size_t grpbase = (size_t)(blockIdx.x * 8 + rp * 4);
    f32x4 zero = {0.f, 0.f, 0.f, 0.f};
    f32x4 acc[4][4];
    #pragma unroll
    for (int i = 0; i < 4; ++i)
        #pragma unroll
        for (int j = 0; j < 4; ++j) acc[i][j] = zero;
    const int bb2[12] = {0, 4, 8, 12, 16, 20, 24, 28, 0, 4, 8, 12};
    #pragma unroll
    for (int s = 0; s < 12; ++s) {
        short8 bfr[4], afr[4];
        #pragma unroll
        for (int ct = 0; ct < 4; ++ct)
            bfr[ct] = *(const short8*)&B2[((size_t)(s * 16 + q * 4 + ct) * 64 + g * 16 + u) * 8];
        #pragma unroll
        for (int rt = 0; rt < 4; ++rt)
            afr[rt] = *(const short8*)&AH[((grpbase + rt) * 32 + bb2[s] + g) * 128 + u * 8];
        #pragma unroll
        for (int rt = 0; rt < 4; ++rt)
            #pragma unroll
            for (int ct = 0; ct < 4; ++ct)
                acc[rt][ct] = __builtin_amdgcn_mfma_f32_16x16x32_bf16(afr[rt], bfr[ct], acc[rt][ct], 0, 0, 0);
    }
    float bgv[4];
    #pragma unroll
    for (int ct = 0; ct < 4; ++ct) bgv[ct] = bg2[q * 64 + ct * 16 + u];
    int hid = q * 16 + u;
    int bhi = 8 + (hid >> 3), blo = 24 + (hid >> 3), el = hid & 7;
    #pragma unroll
    for (int rt = 0; rt < 4; ++rt) {
        size_t rbase = (grpbase + rt) * 4096;
        float ho[4];
        #pragma unroll
        for (int j = 0; j < 4; ++j) {
            int uu = g * 4 + j;
            ho[j] = bf2f(AH[rbase + bhi * 128 + uu * 8 + el])
                  + bf2f(AH[rbase + blo * 128 + uu * 8 + el]);
        }
        #pragma unroll
        for (int j = 0; j < 4; ++j) {
            float rs  = acc[rt][0][j] + bgv[0];
            float zs  = acc[rt][1][j] + bgv[1];
            float inn = acc[rt][2][j] + bgv[2];
            float hnn = acc[rt][3][j] + bgv[3];
            float r = 1.f / (1.f + __expf(-rs));
            float z = 1.f / (1.f + __expf(-zs));
            float nn = tanhf(inn + r * hnn);
            float hnew = (1.f - z) * nn + z * ho[j];
            int rl = rp * 64 + rt * 16 + g * 4 + j;
            ushort_t hh = f2bf(hnew);
            hl[rl * 136 + hid] = hh;
            hl[rl * 136 + 64 + hid] = f2bf(hnew - bf2f(hh));
        }
    }
    __syncthreads();
    // pack-out: 8 groups x 16 blocks x 16 u = 2048 short8 chunks, coalesced
    #pragma unroll
    for (int k = 0; k < 4; ++k) {
        int c = tid + k * 512;
        int gi = c >> 8, r = c & 255, bi = r >> 4, uu = r & 15;
        int row = gi * 16 + uu;
        int lofs = row * 136 + (bi < 8 ? bi * 8 : 64 + (bi - 8) * 8);
        short8 v = *(const short8*)&hl[lofs];
        int blk = (bi < 8) ? (8 + bi) : (16 + bi);   // h-hi 8..15, h-lo 24..31
        *(short8*)&AH[((size_t)(blockIdx.x * 8 + gi) * 32 + blk) * 128 + uu * 8] = v;
    }
}

// ---------------- aggregation via CSR; 1 node per wave, unroll-8 MLP ----------------
__global__ __launch_bounds__(1024) void k_aggregate(const int* __restrict__ row_ptr,
        const int* __restrict__ adj, const ushort_t* __restrict__ trans,
        ushort_t* __restrict__ AH) {
    __shared__ float alds[16 * 72];
    int w = threadIdx.x >> 6, lane = threadIdx.x & 63;
    int grp = blockIdx.x;
    int n = grp * 16 + w;          // always < N_NODES (6250*16 == 100000)
    int beg = row_ptr[n], end = row_ptr[n + 1];
    float a0 = 0.f, a1 = 0.f, a2 = 0.f, a3 = 0.f;
    int i = beg;
    for (; i + 8 <= end; i += 8) {
        int pk[8];
        #pragma unroll
        for (int t = 0; t < 8; ++t) pk[t] = adj[i + t];
        float v[8];
        #pragma unroll
        for (int t = 0; t < 8; ++t)
            v[t] = bf2f(trans[(size_t)(pk[t] & 0xFFFFF) * 256 + (pk[t] >> 20) * 64 + lane]);
        a0 += v[0] + v[4]; a1 += v[1] + v[5]; a2 += v[2] + v[6]; a3 += v[3] + v[7];
    }
    for (; i + 2 <= end; i += 2) {
        int pk0 = adj[i], pk1 = adj[i + 1];
        a0 += bf2f(trans[(size_t)(pk0 & 0xFFFFF) * 256 + (pk0 >> 20) * 64 + lane]);
        a1 += bf2f(trans[(size_t)(pk1 & 0xFFFFF) * 256 + (pk1 >> 20) * 64 + lane]);
    }
    if (i < end) {
        int pk = adj[i];
        a2 += bf2f(trans[(size_t)(pk & 0xFFFFF) * 256 + (pk >> 20) * 64 + lane]);
    }
    alds[w * 72 + lane] = (a0 + a1) + (a2 + a3);
    __syncthreads();
    if (threadIdx.x < 256) {
        int bi = threadIdx.x >> 4, u = threadIdx.x & 15;
        int b8 = bi & 7;
        bool ishi = bi < 8;
        short8 ov;
        #pragma unroll
        for (int j = 0; j < 8; ++j) {
            float v = alds[u * 72 + b8 * 8 + j];
            ushort_t hh = f2bf(v);
            ov[j] = ishi ? (short)hh : (short)f2bf(v - bf2f(hh));
        }
        *(short8*)&AH[((size_t)grp * 32 + (ishi ? b8 : 16 + b8)) * 128 + u * 8] = ov;
    }
}

// ---------------- per-graph mean pooling ----------------
__global__ __launch_bounds__(256) void k_pool(const int* __restrict__ n2g,
        const ushort_t* __restrict__ AH, float* __restrict__ hg) {
    int gidx = blockIdx.x;
    int lo = 0, hi = N_NODES;
    while (lo < hi) { int mid = (lo + hi) >> 1; if (n2g[mid] < gidx) lo = mid + 1; else hi = mid; }
    int s = lo;
    hi = N_NODES;
    while (lo < hi) { int mid = (lo + hi) >> 1; if (n2g[mid] < gidx + 1) lo = mid + 1; else hi = mid; }
    int e = lo;
    int w = threadIdx.x >> 6, lane = threadIdx.x & 63;
    int bh = 8 + (lane >> 3), bl = 24 + (lane >> 3), el = lane & 7;
    float sum = 0.f;
    for (int n = s + w; n < e; n += 4) {
        size_t base = (size_t)(n >> 4) * 4096 + (size_t)(n & 15) * 8;
        sum += bf2f(AH[base + bh * 128 + el]) + bf2f(AH[base + bl * 128 + el]);
    }
    __shared__ float red[4][64];
    red[w][lane] = sum;
    __syncthreads();
    if (threadIdx.x < 64) {
        float tot = red[0][lane] + red[1][lane] + red[2][lane] + red[3][lane];
        float cnt = (float)(e - s);
        hg[gidx * 64 + lane] = tot / fmaxf(cnt, 1.f);
    }
}

// ---------------- classifier ----------------
__global__ __launch_bounds__(64) void k_cls(const float* __restrict__ hg,
        const float* __restrict__ W1, const float* __restrict__ b1,
        const float* __restrict__ W2, const float* __restrict__ b2,
        float* __restrict__ out) {
    int gidx = blockIdx.x;
    __shared__ float v[64];
    __shared__ float m[32];
    v[threadIdx.x] = hg[gidx * 64 + threadIdx.x];
    __syncthreads();
    if (threadIdx.x < 32) {
        float a = b1[threadIdx.x];
        #pragma unroll 8
        for (int k = 0; k < 64; ++k) a = fmaf(v[k], W1[threadIdx.x * 64 + k], a);
        m[threadIdx.x] = fmaxf(a, 0.f);
    }
    __syncthreads();
    if (threadIdx.x < 10) {
        float a = b2[threadIdx.x];
        #pragma unroll
        for (int j = 0; j < 32; ++j) a = fmaf(m[j], W2[threadIdx.x * 32 + j], a);
        out[gidx * 10 + threadIdx.x] = a;
    }
}

extern "C" void kernel_launch(void* const* d_in, const int* in_sizes, int n_in,
                              void* d_out, int out_size, void* d_ws, size_t ws_size,
                              hipStream_t stream) {
    const float* x    = (const float*)d_in[0];
    const int* src    = (const int*)d_in[1];
    const int* dst    = (const int*)d_in[2];
    const int* etype  = (const int*)d_in[3];
    const int* n2g    = (const int*)d_in[4];
    const float* W_in = (const float*)d_in[5];
    const float* b_in = (const float*)d_in[6];
    const float* We   = (const float*)d_in[7];
    const float* be   = (const float*)d_in[8];
    const float* W_ih = (const float*)d_in[9];
    const float* b_ih = (const float*)d_in[10];
    const float* W_hh = (const float*)d_in[11];
    const float* b_hh = (const float*)d_in[12];
    const float* W1   = (const float*)d_in[13];
    const float* b1   = (const float*)d_in[14];
    const float* W2   = (const float*)d_in[15];
    const float* b2   = (const float*)d_in[16];
    float* out = (float*)d_out;

    char* wsb = (char*)d_ws;
    size_t off = 0;
    auto alloc = [&](size_t bytes) -> void* {
        void* p = wsb + off;
        off += (bytes + 255) & ~(size_t)255;
        return p;
    };
    ushort_t* AH      = (ushort_t*)alloc((size_t)NGRP_PAD * 4096 * 2);   // 51.25 MB split [a|h]
    ushort_t* trans   = (ushort_t*)alloc((size_t)N_NODES * 256 * 2);     // 51.2 MB bf16
    int*      adj     = (int*)     alloc((size_t)N_EDGES * 4);
    int*      row_ptr = (int*)     alloc((size_t)(N_NODES + 1) * 4);
    int*      cursor  = (int*)     alloc((size_t)N_NODES * 4);
    int*      deg     = (int*)     alloc((size_t)N_NODES * 4);
    int*      bsum    = (int*)     alloc(1024);
    ushort_t* B1      = (ushort_t*)alloc((size_t)6 * 16 * 4 * 16 * 8 * 2);
    float*    bs1     = (float*)   alloc(256 * 4);
    ushort_t* B2      = (ushort_t*)alloc((size_t)12 * 16 * 4 * 16 * 8 * 2);
    float*    bg2     = (float*)   alloc(256 * 4);
    ushort_t* BIN     = (ushort_t*)alloc((size_t)24576 * 2);
    float*    hg      = (float*)   alloc(128 * 64 * 4);

    // zero padding groups (6250..6255) so mm-block 781's OOB-row reads are finite+deterministic
    hipMemsetAsync(AH + (size_t)NGRP * 4096, 0, (size_t)(NGRP_PAD - NGRP) * 4096 * 2, stream);

    hipLaunchKernelGGL(k_pack_b1, dim3(192), dim3(256), 0, stream, We, be, B1, bs1);
    hipLaunchKernelGGL(k_pack_b2, dim3(384), dim3(256), 0, stream, W_ih, b_ih, W_hh, b_hh, B2, bg2);
    hipLaunchKernelGGL(k_pack_bin, dim3(96), dim3(256), 0, stream, W_in, BIN);
    hipLaunchKernelGGL(k_linear_in, dim3((NGRP + 3) / 4), dim3(256), 0, stream, x, BIN, b_in, AH);

    hipMemsetAsync(deg, 0, (size_t)N_NODES * 4, stream);
    hipLaunchKernelGGL(k_hist, dim3((N_EDGES + 255) / 256), dim3(256), 0, stream, dst, deg);
    int nblk = (N_NODES + 1023) / 1024;
    hipLaunchKernelGGL(k_scan1, dim3(nblk), dim3(256), 0, stream, deg, row_ptr, bsum, N_NODES);
    hipLaunchKernelGGL(k_scan2, dim3(1), dim3(64), 0, stream, bsum, nblk, row_ptr + N_NODES);
    hipLaunchKernelGGL(k_scan3, dim3((N_NODES + 255) / 256), dim3(256), 0, stream, row_ptr, cursor, bsum, N_NODES);
    hipLaunchKernelGGL(k_fill, dim3((N_EDGES + 255) / 256), dim3(256), 0, stream, src, dst, etype, cursor, adj);

    int gblk = NGRP_PAD / 8;   // 782
    for (int step = 0; step < STEPS; ++step) {
        hipLaunchKernelGGL(k_mm1, dim3(gblk), dim3(512), 0, stream, AH, B1, bs1, trans);
        hipLaunchKernelGGL(k_aggregate, dim3(NGRP), dim3(1024), 0, stream, row_ptr, adj, trans, AH);
        hipLaunchKernelGGL(k_mm2, dim3(gblk), dim3(512), 0, stream, AH, B2, bg2);
    }
    hipLaunchKernelGGL(k_pool, dim3(G_GRAPHS), dim3(256), 0, stream, n2g, AH, hg);
    hipLaunchKernelGGL(k_cls, dim3(G_GRAPHS), dim3(64), 0, stream, hg, W1, b1, W2, b2, out);
}